// Round 9
// baseline (658.885 us; speedup 1.0000x reference)
//
#include <hip/hip_runtime.h>
#include <math.h>

#define NBS 1600      // B*S
#define LL 20
#define EE 300
#define NH 16
#define VD 16
#define HID 256
#define QD 200

typedef short bf16x8 __attribute__((ext_vector_type(8)));
typedef float f32x4 __attribute__((ext_vector_type(4)));

__device__ __forceinline__ short f2b(float f) {
    union { float f; unsigned u; } c; c.f = f;
    unsigned r = (c.u + 0x7FFFu + ((c.u >> 16) & 1u)) >> 16;  // RNE
    return (short)r;
}

__device__ __forceinline__ float ftanh(float a) {
    a = fminf(fmaxf(a, -15.f), 15.f);
    float t = __expf(2.f * a);
    return (t - 1.f) / (t + 1.f);
}

// ===========================================================================
// NEW PATH (needs ~40.4 MB ws)
// ===========================================================================

// news/emb -> Xb bf16 [32000][320]; col300 = 1.0 (bias channel), 301..319 = 0
__global__ void build_xb(const int* __restrict__ news, const float* __restrict__ emb,
                         short* __restrict__ Xb) {
    int idx = blockIdx.x * 256 + threadIdx.x;     // one per 4 elems
    if (idx >= 32000 * 80) return;
    int i = idx / 80, e4 = (idx % 80) * 4;
    short4 o;
    if (e4 < 300) {
        const float4 v = *reinterpret_cast<const float4*>(emb + (size_t)news[i] * EE + e4);
        o.x = f2b(v.x); o.y = f2b(v.y); o.z = f2b(v.z); o.w = f2b(v.w);
    } else if (e4 == 300) {
        o.x = (short)0x3F80; o.y = 0; o.z = 0; o.w = 0;
    } else {
        o.x = o.y = o.z = o.w = 0;
    }
    *reinterpret_cast<short4*>(Xb + (size_t)i * 320 + e4) = o;
}

// Wq [n][e][f] -> WqT bf16 [n][f(320)][e(320)], col300 = qB, zero rows f>=300
__global__ __launch_bounds__(1024) void build_wqt(
    const float* __restrict__ qW, const float* __restrict__ qB, short* __restrict__ WqT)
{
    __shared__ float t[32][33];
    const int n = blockIdx.z;
    const int e0 = blockIdx.x * 32, f0 = blockIdx.y * 32;
    const int tx = threadIdx.x, ty = threadIdx.y;
    const int e = e0 + ty, f = f0 + tx;
    t[ty][tx] = (e < EE && f < EE) ? qW[((size_t)n * EE + e) * EE + f] : 0.f;
    __syncthreads();
    const int fo = f0 + ty, eo = e0 + tx;
    float val;
    if (fo >= EE)      val = 0.f;
    else if (eo < EE)  val = t[tx][ty];
    else if (eo == EE) val = qB[n * EE + fo];
    else               val = 0.f;
    WqT[((size_t)n * 320 + fo) * 320 + eo] = f2b(val);
}

// Wv [n][e][v] -> WvT bf16 [256][320] rows c=n*16+vd, col300 = vB
__global__ void build_wvt(const float* __restrict__ vW, const float* __restrict__ vB,
                          short* __restrict__ WvT) {
    int idx = blockIdx.x * 256 + threadIdx.x;
    if (idx >= 256 * 320) return;
    int c = idx / 320, e = idx % 320;
    int n = c >> 4, vd = c & 15;
    float val = (e < EE) ? vW[((size_t)n * EE + e) * VD + vd]
                         : (e == EE ? vB[n * VD + vd] : 0.f);
    WvT[idx] = f2b(val);
}

// keyW [200][256] fp32 -> bf16 [208][256] (rows >=200 zero)
__global__ void conv_kw(const float* __restrict__ keyW, short* __restrict__ kwb) {
    int idx = blockIdx.x * 256 + threadIdx.x;
    if (idx >= 208 * 256) return;
    int d = idx >> 8;
    kwb[idx] = (d < QD) ? f2b(keyW[idx]) : (short)0;
}

// xv = Xb * WvT^T : [32000][256] bf16.  128x128 tile, 4 waves.
__global__ __launch_bounds__(256) void gemm_xv(
    const short* __restrict__ Xb, const short* __restrict__ WvT, short* __restrict__ xv)
{
    const int nt0 = blockIdx.x * 128;
    const size_t mt0 = (size_t)blockIdx.y * 128;
    const int tid = threadIdx.x, wave = tid >> 6, lane = tid & 63;
    const int lr = lane & 15, lg = lane >> 4;
    const int wm = wave & 1, wn = wave >> 1;

    __shared__ short As[128][68];
    __shared__ short Bs[128][68];
    f32x4 acc[4][4] = {};

    for (int ks = 0; ks < 5; ++ks) {
        __syncthreads();
        for (int u = 0; u < 4; ++u) {
            int idx = u * 256 + tid;          // 0..1023
            int rr = idx >> 3, c8 = idx & 7;
            *reinterpret_cast<bf16x8*>(&As[rr][c8 * 8]) =
                *reinterpret_cast<const bf16x8*>(Xb + (mt0 + rr) * 320 + ks * 64 + c8 * 8);
            *reinterpret_cast<bf16x8*>(&Bs[rr][c8 * 8]) =
                *reinterpret_cast<const bf16x8*>(WvT + (size_t)(nt0 + rr) * 320 + ks * 64 + c8 * 8);
        }
        __syncthreads();
        #pragma unroll
        for (int kk = 0; kk < 2; ++kk) {
            bf16x8 af[4], bfv[4];
            #pragma unroll
            for (int f = 0; f < 4; ++f)
                af[f] = *reinterpret_cast<const bf16x8*>(&As[wm * 64 + f * 16 + lr][kk * 32 + lg * 8]);
            #pragma unroll
            for (int f = 0; f < 4; ++f)
                bfv[f] = *reinterpret_cast<const bf16x8*>(&Bs[wn * 64 + f * 16 + lr][kk * 32 + lg * 8]);
            #pragma unroll
            for (int i = 0; i < 4; ++i)
                #pragma unroll
                for (int j = 0; j < 4; ++j)
                    acc[i][j] = __builtin_amdgcn_mfma_f32_16x16x32_bf16(af[i], bfv[j], acc[i][j], 0, 0, 0);
        }
    }
    #pragma unroll
    for (int i = 0; i < 4; ++i)
        #pragma unroll
        for (int j = 0; j < 4; ++j)
            #pragma unroll
            for (int r = 0; r < 4; ++r)
                xv[(mt0 + wm * 64 + i * 16 + lg * 4 + r) * 256 + nt0 + wn * 64 + j * 16 + lr]
                    = f2b(acc[i][j][r]);
}

// ---------------------------------------------------------------------------
// qattn v6: one block per (80 rows = 4 bs, head). 256 threads, 4 waves (1Mx4N,
// wave tile 80x80, 5x5 acc). LDS 79.0 KB -> 2 blocks/CU (drain overlap via
// the co-resident block, m114). Staging coalesced: 4 lanes share one row's
// 64B. atw aliases qs (dead after scores).
// ---------------------------------------------------------------------------
__global__ __launch_bounds__(256, 2) void qattn(
    const short* __restrict__ Xb,    // [32000][320]
    const short* __restrict__ WqT,   // [16][320][320]
    const short* __restrict__ xv,    // [32000][256]
    float*       __restrict__ out1)  // [32000][256]
{
    const int g = blockIdx.x;        // 80-row chunk (4 bs)
    const int n = blockIdx.y;        // head
    const int tid = threadIdx.x, wave = tid >> 6, lane = tid & 63;
    const int lr = lane & 15, lg = lane >> 4;
    const size_t row0 = (size_t)g * 80;

    // LDS manual layout (79040 B total):
    //  [0, 25920)        qs [80][324]  -- after scores, atw [4][32][34] aliases here
    //  [25920, 28640)    Asg [80][34]
    //  [28640, 39520)    Bsg [320][34]
    __shared__ short lds[39520];
    short* qs  = lds;
    short* Asg = lds + 25920;
    short* Bsg = lds + 28640;
    short* atw = lds;                // alias over qs

    const short* wh = WqT + (size_t)n * 102400;

    // ---- staging map: 1600 segs of 16B (A: 80x4 = 320, B: 320x4 = 1280) ----
    // thread t handles segs s = t + k*256, k = 0..6 (k==6 only t<64).
    const short* gp[7];
    short*       lp[7];
    #pragma unroll
    for (int k = 0; k < 7; ++k) {
        const int s = tid + k * 256;
        if (s < 320) {
            gp[k] = Xb + (row0 + (s >> 2)) * 320 + (s & 3) * 8;
            lp[k] = Asg + (s >> 2) * 34 + (s & 3) * 8;
        } else {
            const int s2 = (s < 1600) ? s - 320 : 0;
            gp[k] = wh + (size_t)(s2 >> 2) * 320 + (s2 & 3) * 8;
            lp[k] = Bsg + (s2 >> 2) * 34 + (s2 & 3) * 8;
        }
    }

    // prefetch xv B-frag for v-phase (wave = bs)
    bf16x8 bv;
    {
        const int b = wave;
        #pragma unroll
        for (int j = 0; j < 8; ++j) {
            int m = lg * 8 + j; if (m > 19) m = 19;   // attn cols >=20 are zero
            bv[j] = xv[(row0 + b * 20 + m) * 256 + n * 16 + lr];
        }
    }

    // prefetch staging chunk 0
    bf16x8 st[7];
    #pragma unroll
    for (int k = 0; k < 6; ++k) st[k] = *reinterpret_cast<const bf16x8*>(gp[k]);
    if (tid < 64) st[6] = *reinterpret_cast<const bf16x8*>(gp[6]);

    // ---- q-GEMM K-loop: M=80, N=320 (wave n-quarter), K=320 (10 chunks) ----
    f32x4 acc[5][5] = {};
    for (int ks = 0; ks < 10; ++ks) {
        __syncthreads();                       // stage buffers free
        #pragma unroll
        for (int k = 0; k < 6; ++k) *reinterpret_cast<bf16x8*>(lp[k]) = st[k];
        if (tid < 64) *reinterpret_cast<bf16x8*>(lp[6]) = st[6];
        __syncthreads();                       // stage ready
        if (ks < 9) {                          // issue next chunk (flies over MFMAs)
            const int off = (ks + 1) * 32;
            #pragma unroll
            for (int k = 0; k < 6; ++k) st[k] = *reinterpret_cast<const bf16x8*>(gp[k] + off);
            if (tid < 64) st[6] = *reinterpret_cast<const bf16x8*>(gp[6] + off);
        }
        bf16x8 af[5], bfr[5];
        #pragma unroll
        for (int i = 0; i < 5; ++i)
            af[i] = *reinterpret_cast<const bf16x8*>(Asg + (i * 16 + lr) * 34 + lg * 8);
        #pragma unroll
        for (int j = 0; j < 5; ++j)
            bfr[j] = *reinterpret_cast<const bf16x8*>(Bsg + (wave * 80 + j * 16 + lr) * 34 + lg * 8);
        #pragma unroll
        for (int i = 0; i < 5; ++i)
            #pragma unroll
            for (int j = 0; j < 5; ++j)
                acc[i][j] = __builtin_amdgcn_mfma_f32_16x16x32_bf16(af[i], bfr[j], acc[i][j], 0, 0, 0);
    }

    // ---- acc -> qs (bf16); cols wave*80 + j*16 + lr ----
    #pragma unroll
    for (int i = 0; i < 5; ++i)
        #pragma unroll
        for (int j = 0; j < 5; ++j)
            #pragma unroll
            for (int r = 0; r < 4; ++r)
                qs[(i * 16 + lg * 4 + r) * 324 + wave * 80 + j * 16 + lr] = f2b(acc[i][j][r]);

    // ---- bulk-prefetch scores-phase X fragments ----
    const int b = wave;
    const int rA0 = b * 20 + lr;
    int rA1 = b * 20 + 16 + lr; if (rA1 > 79) rA1 = 79;
    const size_t rB0g = row0 + b * 20 + lr;
    size_t rB1g = row0 + rA1;

    bf16x8 xpre0[10], xpre1[10];
    #pragma unroll
    for (int ks = 0; ks < 10; ++ks) {
        xpre0[ks] = *reinterpret_cast<const bf16x8*>(Xb + rB0g * 320 + ks * 32 + lg * 8);
        xpre1[ks] = *reinterpret_cast<const bf16x8*>(Xb + rB1g * 320 + ks * 32 + lg * 8);
    }
    __syncthreads();   // qs complete

    // ---- scores + in-register softmax: wave = bs ----
    float w0[2][4], w1[2][4];    // normalized attn values to write after barrier
    {
        f32x4 s[2][2] = {};
        #pragma unroll
        for (int ks = 0; ks < 10; ++ks) {
            const int kc = ks * 32 + lg * 8;
            bf16x8 a0 = *reinterpret_cast<const bf16x8*>(qs + rA0 * 324 + kc);
            bf16x8 a1 = *reinterpret_cast<const bf16x8*>(qs + rA1 * 324 + kc);
            s[0][0] = __builtin_amdgcn_mfma_f32_16x16x32_bf16(a0, xpre0[ks], s[0][0], 0, 0, 0);
            s[0][1] = __builtin_amdgcn_mfma_f32_16x16x32_bf16(a0, xpre1[ks], s[0][1], 0, 0, 0);
            s[1][0] = __builtin_amdgcn_mfma_f32_16x16x32_bf16(a1, xpre0[ks], s[1][0], 0, 0, 0);
            s[1][1] = __builtin_amdgcn_mfma_f32_16x16x32_bf16(a1, xpre1[ks], s[1][1], 0, 0, 0);
        }

        const float scl = 0.057735026918962584f;  // 1/sqrt(300)
        #pragma unroll
        for (int mts = 0; mts < 2; ++mts) {
            #pragma unroll
            for (int r = 0; r < 4; ++r) {
                float v0 = s[mts][0][r] * scl;
                float v1 = s[mts][1][r] * scl;
                float mx = (lr < 4) ? fmaxf(v0, v1) : v0;
                mx = fmaxf(mx, __shfl_xor(mx, 1));
                mx = fmaxf(mx, __shfl_xor(mx, 2));
                mx = fmaxf(mx, __shfl_xor(mx, 4));
                mx = fmaxf(mx, __shfl_xor(mx, 8));
                float e0 = __expf(v0 - mx);
                float e1 = (lr < 4) ? __expf(v1 - mx) : 0.f;
                float sm = e0 + e1;
                sm += __shfl_xor(sm, 1);
                sm += __shfl_xor(sm, 2);
                sm += __shfl_xor(sm, 4);
                sm += __shfl_xor(sm, 8);
                const float inv = 1.f / sm;
                w0[mts][r] = e0 * inv;
                w1[mts][r] = e1 * inv;
            }
        }
    }
    __syncthreads();   // all waves done reading qs -> safe to alias atw

    // ---- write attn into atw [4][32][34] (aliases qs) ----
    #pragma unroll
    for (int mts = 0; mts < 2; ++mts)
        #pragma unroll
        for (int r = 0; r < 4; ++r) {
            const int row = mts * 16 + lg * 4 + r;
            if (row < LL) {
                atw[(b * 32 + row) * 34 + lr]      = f2b(w0[mts][r]);
                atw[(b * 32 + row) * 34 + 16 + lr] = f2b(w1[mts][r]);  // lr>=4 writes 0
            }
        }
    __syncthreads();

    // ---- v = attn * xv : wave = bs, both mt tiles ----
    {
        bf16x8 va0 = *reinterpret_cast<const bf16x8*>(atw + (b * 32 + lr) * 34 + lg * 8);
        bf16x8 va1 = *reinterpret_cast<const bf16x8*>(atw + (b * 32 + 16 + lr) * 34 + lg * 8);
        f32x4 z = {0.f, 0.f, 0.f, 0.f};
        f32x4 v0 = __builtin_amdgcn_mfma_f32_16x16x32_bf16(va0, bv, z, 0, 0, 0);
        f32x4 v1 = __builtin_amdgcn_mfma_f32_16x16x32_bf16(va1, bv, z, 0, 0, 0);
        #pragma unroll
        for (int r = 0; r < 4; ++r) {
            const int rowl = lg * 4 + r;
            out1[(row0 + b * 20 + rowl) * 256 + n * 16 + lr] = v0[r];
            const int rowl1 = 16 + lg * 4 + r;
            if (rowl1 < LL)
                out1[(row0 + b * 20 + rowl1) * 256 + n * 16 + lr] = v1[r];
        }
    }
}

// ---------------------------------------------------------------------------
// Additive attention pooling per bs, MFMA add_key. grid 1600, block 256.
// ---------------------------------------------------------------------------
__global__ __launch_bounds__(256) void nrms_pool_mfma(
    const float* __restrict__ out1,
    const short* __restrict__ kwb,    // [208][256] bf16
    const float* __restrict__ keyB,   // [200]
    const float* __restrict__ query,  // [200]
    float*       __restrict__ out2)   // [NBS][256]
{
    const int bs   = blockIdx.x;
    const int tid  = threadIdx.x;
    const int wave = tid >> 6;
    const int lane = tid & 63;
    const int lr   = lane & 15;
    const int lg   = lane >> 4;

    __shared__ float mh[LL][257];
    __shared__ short mhb[32][264];   // 132 dw == 4 mod 32
    __shared__ float s2p[32];

    for (int i = tid; i < 12 * 128; i += 256) {
        const int r = 20 + i / 128, c = (i % 128) * 2;
        *reinterpret_cast<int*>(&mhb[r][c]) = 0;
    }
    if (tid < 32) s2p[tid] = 0.f;

    for (int idx = tid; idx < LL * 64; idx += 256) {
        const int l = idx >> 6, h4 = (idx & 63) * 4;
        const float4 v = *reinterpret_cast<const float4*>(out1 + ((size_t)bs * LL + l) * HID + h4);
        mh[l][h4] = v.x; mh[l][h4 + 1] = v.y; mh[l][h4 + 2] = v.z; mh[l][h4 + 3] = v.w;
        mhb[l][h4] = f2b(v.x); mhb[l][h4 + 1] = f2b(v.y);
        mhb[l][h4 + 2] = f2b(v.z); mhb[l][h4 + 3] = f2b(v.w);
    }
    __syncthreads();

    for (int t = wave; t < 26; t += 4) {
        const int mt = t & 1, nt = t >> 1;
        f32x4 acc = {0.f, 0.f, 0.f, 0.f};
        const short* ap = &mhb[mt * 16 + lr][lg * 8];
        const short* bp = kwb + (nt * 16 + lr) * 256 + lg * 8;
        #pragma unroll
        for (int k = 0; k < 8; ++k) {
            bf16x8 a = *reinterpret_cast<const bf16x8*>(ap + k * 32);
            bf16x8 b = *reinterpret_cast<const bf16x8*>(bp + k * 32);
            acc = __builtin_amdgcn_mfma_f32_16x16x32_bf16(a, b, acc, 0, 0, 0);
        }
        const int d = nt * 16 + lr;
        const float qd = (d < QD) ? query[d] : 0.f;
        const float kb = (d < QD) ? keyB[d] : 0.f;
        float vals[4];
        #pragma unroll
        for (int r = 0; r < 4; ++r) vals[r] = qd * ftanh(acc[r] + kb);
        #pragma unroll
        for (int off = 1; off < 16; off <<= 1) {
            #pragma unroll
            for (int r = 0; r < 4; ++r) vals[r] += __shfl_xor(vals[r], off);
        }
        if (lr == 0) {
            #pragma unroll
            for (int r = 0; r < 4; ++r)
                atomicAdd(&s2p[mt * 16 + lg * 4 + r], vals[r]);
        }
    }
    __syncthreads();

    if (tid == 0) {
        float mx = -1e30f;
        #pragma unroll
        for (int l = 0; l < LL; ++l) mx = fmaxf(mx, s2p[l] * 0.07071067811865475f);
        float sum = 0.f;
        float e[LL];
        #pragma unroll
        for (int l = 0; l < LL; ++l) { e[l] = __expf(s2p[l] * 0.07071067811865475f - mx); sum += e[l]; }
        const float inv = 1.f / sum;
        #pragma unroll
        for (int l = 0; l < LL; ++l) s2p[l] = e[l] * inv;
    }
    __syncthreads();

    {
        const int h = tid;
        float acc = 0.f;
        #pragma unroll
        for (int l = 0; l < LL; ++l) acc = fmaf(s2p[l], mh[l][h], acc);
        out2[(size_t)bs * HID + h] = acc;
    }
}

// ===========================================================================
// FALLBACK PATH (round-3, needs only 3.4 MB ws) — used if ws_size too small
// ===========================================================================

#define XP 330
#define TP 42
#define AP 34

__global__ __launch_bounds__(1024) void transpose_qw(
    const float* __restrict__ qW, short* __restrict__ wqt)
{
    __shared__ float t[32][33];
    const int n = blockIdx.z;
    const int e0 = blockIdx.x * 32, f0 = blockIdx.y * 32;
    const int tx = threadIdx.x, ty = threadIdx.y;
    const int e = e0 + ty, f = f0 + tx;
    t[ty][tx] = (e < EE && f < EE) ? qW[(size_t)n * EE * EE + e * EE + f] : 0.f;
    __syncthreads();
    const int fo = f0 + ty, eo = e0 + tx;
    if (fo < 304)
        wqt[(size_t)n * 304 * 320 + fo * 320 + eo] = f2b(t[tx][ty]);
}

__global__ void conv_vw(const float* __restrict__ vW, short* __restrict__ wvt) {
    int idx = blockIdx.x * 256 + threadIdx.x;
    if (idx >= NH * VD * 320) return;
    int e = idx % 320;
    int v = (idx / 320) % VD;
    int n = idx / (320 * VD);
    wvt[idx] = (e < EE) ? f2b(vW[(size_t)n * EE * VD + e * VD + v]) : (short)0;
}

__global__ __launch_bounds__(512) void nrms_attn_mfma(
    const int*   __restrict__ news,
    const float* __restrict__ emb,
    const short* __restrict__ wqt,
    const float* __restrict__ qB,
    const short* __restrict__ wvt,
    const float* __restrict__ vB,
    float*       __restrict__ out1)
{
    const int bs   = blockIdx.x;
    const int tid  = threadIdx.x;
    const int wave = tid >> 6;
    const int lane = tid & 63;
    const int lr   = lane & 15;
    const int lg   = lane >> 4;

    __shared__ short xs[32][XP];
    __shared__ short xT[320][TP];
    __shared__ short qs[32][XP];
    __shared__ float sc[32][33];
    __shared__ short at[32][AP];

    {
        int* z = (int*)&xs[0][0];
        for (int i = tid; i < 32 * XP / 2; i += 512) z[i] = 0;
        z = (int*)&qs[0][0];
        for (int i = tid; i < 32 * XP / 2; i += 512) z[i] = 0;
        z = (int*)&xT[0][0];
        for (int i = tid; i < 320 * TP / 2; i += 512) z[i] = 0;
    }
    __syncthreads();

    for (int idx = tid; idx < LL * 75; idx += 512) {
        const int l = idx / 75, e4 = (idx % 75) * 4;
        const int row = news[bs * LL + l];
        const float4 v = *reinterpret_cast<const float4*>(emb + (size_t)row * EE + e4);
        const short b0 = f2b(v.x), b1 = f2b(v.y), b2 = f2b(v.z), b3 = f2b(v.w);
        xs[l][e4] = b0; xs[l][e4 + 1] = b1; xs[l][e4 + 2] = b2; xs[l][e4 + 3] = b3;
        xT[e4][l] = b0; xT[e4 + 1][l] = b1; xT[e4 + 2][l] = b2; xT[e4 + 3][l] = b3;
    }
    __syncthreads();

    for (int n = 0; n < NH; ++n) {
        const short* wq = wqt + (size_t)n * 304 * 320;

        for (int p = wave; p < 19; p += 8) {
            f32x4 acc0 = {0.f, 0.f, 0.f, 0.f};
            f32x4 acc1 = {0.f, 0.f, 0.f, 0.f};
            const short* a0p = &xs[lr][lg * 8];
            const short* a1p = &xs[16 + lr][lg * 8];
            const short* bp  = wq + (p * 16 + lr) * 320 + lg * 8;
            #pragma unroll
            for (int k = 0; k < 10; ++k) {
                bf16x8 b  = *reinterpret_cast<const bf16x8*>(bp + k * 32);
                bf16x8 a0 = *reinterpret_cast<const bf16x8*>(a0p + k * 32);
                bf16x8 a1 = *reinterpret_cast<const bf16x8*>(a1p + k * 32);
                acc0 = __builtin_amdgcn_mfma_f32_16x16x32_bf16(a0, b, acc0, 0, 0, 0);
                acc1 = __builtin_amdgcn_mfma_f32_16x16x32_bf16(a1, b, acc1, 0, 0, 0);
            }
            const int col = p * 16 + lr;
            const float bias = (col < EE) ? qB[n * EE + col] : 0.f;
            #pragma unroll
            for (int r = 0; r < 4; ++r) {
                qs[lg * 4 + r][col]      = f2b(acc0[r] + bias);
                qs[16 + lg * 4 + r][col] = f2b(acc1[r] + bias);
            }
        }
        __syncthreads();

        if (wave < 4) {
            const int mt = wave & 1, nt = wave >> 1;
            f32x4 acc = {0.f, 0.f, 0.f, 0.f};
            const short* ap = &qs[mt * 16 + lr][lg * 8];
            const short* bp = &xs[nt * 16 + lr][lg * 8];
            #pragma unroll
            for (int k = 0; k < 10; ++k) {
                bf16x8 a = *reinterpret_cast<const bf16x8*>(ap + k * 32);
                bf16x8 b = *reinterpret_cast<const bf16x8*>(bp + k * 32);
                acc = __builtin_amdgcn_mfma_f32_16x16x32_bf16(a, b, acc, 0, 0, 0);
            }
            #pragma unroll
            for (int r = 0; r < 4; ++r)
                sc[mt * 16 + lg * 4 + r][nt * 16 + lr] = acc[r] * 0.057735026918962584f;
        }
        __syncthreads();

        if (tid < LL) {
            float mx = -1e30f;
            #pragma unroll
            for (int m = 0; m < LL; ++m) mx = fmaxf(mx, sc[tid][m]);
            float ev[LL], sum = 0.f;
            #pragma unroll
            for (int m = 0; m < LL; ++m) { ev[m] = __expf(sc[tid][m] - mx); sum += ev[m]; }
            const float inv = 1.f / sum;
            #pragma unroll
            for (int m = 0; m < LL; ++m) at[tid][m] = f2b(ev[m] * inv);
            #pragma unroll
            for (int m = LL; m < 32; ++m) at[tid][m] = 0;
        } else if (tid < 32) {
            int* zr = (int*)&at[tid][0];
            #pragma unroll
            for (int m = 0; m < 16; ++m) zr[m] = 0;
        }
        __syncthreads();

        for (int p = wave; p < 19; p += 8) {
            bf16x8 b  = *reinterpret_cast<const bf16x8*>(&xT[p * 16 + lr][lg * 8]);
            bf16x8 a0 = *reinterpret_cast<const bf16x8*>(&at[lr][lg * 8]);
            bf16x8 a1 = *reinterpret_cast<const bf16x8*>(&at[16 + lr][lg * 8]);
            f32x4 z = {0.f, 0.f, 0.f, 0.f};
            f32x4 c0 = __builtin_amdgcn_mfma_f32_16x16x32_bf16(a0, b, z, 0, 0, 0);
            f32x4 c1 = __builtin_amdgcn_mfma_f32_16x16x32_bf16(a1, b, z, 0, 0, 0);
            const int col = p * 16 + lr;
            #pragma unroll
            for (int r = 0; r < 4; ++r) {
                qs[lg * 4 + r][col]      = f2b(c0[r]);
                qs[16 + lg * 4 + r][col] = f2b(c1[r]);
            }
        }
        __syncthreads();

        if (wave < 2) {
            const int mt = wave;
            f32x4 acc = {0.f, 0.f, 0.f, 0.f};
            const short* ap = &qs[mt * 16 + lr][lg * 8];
            const short* bp = wvt + (size_t)n * VD * 320 + lr * 320 + lg * 8;
            #pragma unroll
            for (int k = 0; k < 10; ++k) {
                bf16x8 a = *reinterpret_cast<const bf16x8*>(ap + k * 32);
                bf16x8 b = *reinterpret_cast<const bf16x8*>(bp + k * 32);
                acc = __builtin_amdgcn_mfma_f32_16x16x32_bf16(a, b, acc, 0, 0, 0);
            }
            #pragma unroll
            for (int r = 0; r < 4; ++r) {
                const int row = mt * 16 + lg * 4 + r;
                if (row < LL)
                    out1[((size_t)bs * LL + row) * HID + n * VD + lr] = acc[r] + vB[n * VD + lr];
            }
        }
        __syncthreads();
    }
}

// ===========================================================================

extern "C" void kernel_launch(void* const* d_in, const int* in_sizes, int n_in,
                              void* d_out, int out_size, void* d_ws, size_t ws_size,
                              hipStream_t stream) {
    const int*   news  = (const int*)d_in[0];
    const float* emb   = (const float*)d_in[1];
    const float* qW    = (const float*)d_in[2];
    const float* qB    = (const float*)d_in[3];
    const float* vW    = (const float*)d_in[4];
    const float* vB    = (const float*)d_in[5];
    const float* keyW  = (const float*)d_in[6];
    const float* keyB  = (const float*)d_in[7];
    const float* query = (const float*)d_in[8];

    float* out1 = (float*)d_out;            // news_embedding: 8192000 floats
    float* out2 = out1 + 8192000;           // news_repr: 409600 floats

    const size_t NEED = ((size_t)10240000 + 1638400 + 81920 + 8192000 + 53248) * 2;

    if (ws_size >= NEED) {
        short* Xb  = (short*)d_ws;                  // 32000*320
        short* WqT = Xb + 10240000;                 // 16*320*320
        short* WvT = WqT + 1638400;                 // 256*320
        short* xv  = WvT + 81920;                   // 32000*256
        short* kwb = xv + 8192000;                  // 208*256

        hipLaunchKernelGGL(build_xb, dim3(10000), dim3(256), 0, stream, news, emb, Xb);
        hipLaunchKernelGGL(build_wqt, dim3(10, 10, 16), dim3(32, 32), 0, stream, qW, qB, WqT);
        hipLaunchKernelGGL(build_wvt, dim3(320), dim3(256), 0, stream, vW, vB, WvT);
        hipLaunchKernelGGL(conv_kw, dim3(208), dim3(256), 0, stream, keyW, kwb);
        hipLaunchKernelGGL(gemm_xv, dim3(2, 250), dim3(256), 0, stream, Xb, WvT, xv);
        hipLaunchKernelGGL(qattn, dim3(400, 16), dim3(256), 0, stream, Xb, WqT, xv, out1);
        hipLaunchKernelGGL(nrms_pool_mfma, dim3(NBS), dim3(256), 0, stream,
                           out1, kwb, keyB, query, out2);
    } else {
        short* wqt = (short*)d_ws;
        short* wvt = wqt + (size_t)NH * 304 * 320;
        short* kwb = wvt + (size_t)NH * VD * 320;

        hipLaunchKernelGGL(transpose_qw, dim3(10, 10, 16), dim3(32, 32), 0, stream, qW, wqt);
        hipLaunchKernelGGL(conv_vw, dim3(320), dim3(256), 0, stream, vW, wvt);
        hipLaunchKernelGGL(conv_kw, dim3(208), dim3(256), 0, stream, keyW, kwb);
        hipLaunchKernelGGL(nrms_attn_mfma, dim3(NBS), dim3(512), 0, stream,
                           news, emb, wqt, qB, wvt, vB, out1);
        hipLaunchKernelGGL(nrms_pool_mfma, dim3(NBS), dim3(256), 0, stream,
                           out1, kwb, keyB, query, out2);
    }
}

// Round 10
// 490.231 us; speedup vs baseline: 1.3440x; 1.3440x over previous
//
#include <hip/hip_runtime.h>
#include <math.h>

#define NBS 1600      // B*S
#define LL 20
#define EE 300
#define NH 16
#define VD 16
#define HID 256
#define QD 200

typedef short bf16x8 __attribute__((ext_vector_type(8)));
typedef float f32x4 __attribute__((ext_vector_type(4)));

__device__ __forceinline__ short f2b(float f) {
    union { float f; unsigned u; } c; c.f = f;
    unsigned r = (c.u + 0x7FFFu + ((c.u >> 16) & 1u)) >> 16;  // RNE
    return (short)r;
}

__device__ __forceinline__ float ftanh(float a) {
    a = fminf(fmaxf(a, -15.f), 15.f);
    float t = __expf(2.f * a);
    return (t - 1.f) / (t + 1.f);
}

__device__ __forceinline__ void gload16(const short* g, short* l) {
    __builtin_amdgcn_global_load_lds(
        (const __attribute__((address_space(1))) unsigned int*)g,
        (__attribute__((address_space(3))) unsigned int*)l, 16, 0, 0);
}

// ===========================================================================
// NEW PATH (needs ~84.3 MB ws): chunk-padded layouts for global_load_lds
//   Xb_c  [32000][5 chunks][72 shorts]  (64 data + 8 pad per chunk)
//   WqT_c [5120 rows=n*320+f][5][72]
// ===========================================================================

__global__ void build_xb_c(const int* __restrict__ news, const float* __restrict__ emb,
                           short* __restrict__ Xb) {
    int idx = blockIdx.x * 256 + threadIdx.x;       // one per 16B seg
    if (idx >= 32000 * 45) return;
    int i = idx / 45, sg = idx % 45;
    int chunk = sg / 9, part = sg % 9;
    bf16x8 o;
    if (part == 8) {
        for (int j = 0; j < 8; ++j) o[j] = 0;       // pad seg
    } else {
        const int e0 = chunk * 64 + part * 8;
        const float* src = emb + (size_t)news[i] * EE;
        for (int j = 0; j < 8; ++j) {
            const int e = e0 + j;
            float v = (e < 300) ? src[e] : (e == 300 ? 1.f : 0.f);
            o[j] = f2b(v);
        }
    }
    *reinterpret_cast<bf16x8*>(Xb + (size_t)i * 360 + sg * 8) = o;
}

__global__ __launch_bounds__(1024) void build_wqt_c(
    const float* __restrict__ qW, const float* __restrict__ qB, short* __restrict__ WqT)
{
    __shared__ float t[32][33];
    const int n = blockIdx.z;
    const int e0 = blockIdx.x * 32, f0 = blockIdx.y * 32;
    const int tx = threadIdx.x, ty = threadIdx.y;
    const int e = e0 + ty, f = f0 + tx;
    t[ty][tx] = (e < EE && f < EE) ? qW[((size_t)n * EE + e) * EE + f] : 0.f;
    __syncthreads();
    const int fo = f0 + ty, eo = e0 + tx;
    float val;
    if (fo >= EE)      val = 0.f;
    else if (eo < EE)  val = t[tx][ty];
    else if (eo == EE) val = qB[n * EE + fo];
    else               val = 0.f;
    WqT[((size_t)(n * 320 + fo) * 5 + (eo >> 6)) * 72 + (eo & 63)] = f2b(val);
}

// Wv [n][e][v] -> WvT bf16 [256][320] linear (reg-staged consumer)
__global__ void build_wvt(const float* __restrict__ vW, const float* __restrict__ vB,
                          short* __restrict__ WvT) {
    int idx = blockIdx.x * 256 + threadIdx.x;
    if (idx >= 256 * 320) return;
    int c = idx / 320, e = idx % 320;
    int n = c >> 4, vd = c & 15;
    float val = (e < EE) ? vW[((size_t)n * EE + e) * VD + vd]
                         : (e == EE ? vB[n * VD + vd] : 0.f);
    WvT[idx] = f2b(val);
}

__global__ void conv_kw(const float* __restrict__ keyW, short* __restrict__ kwb) {
    int idx = blockIdx.x * 256 + threadIdx.x;
    if (idx >= 208 * 256) return;
    int d = idx >> 8;
    kwb[idx] = (d < QD) ? f2b(keyW[idx]) : (short)0;
}

// xv = Xb * WvT^T, stride-parameterized Xb (works for linear 320/64 and chunked 360/72)
__global__ __launch_bounds__(256) void gemm_xv(
    const short* __restrict__ Xb, const short* __restrict__ WvT, short* __restrict__ xv,
    int xrs, int xcs)
{
    const int nt0 = blockIdx.x * 128;
    const size_t mt0 = (size_t)blockIdx.y * 128;
    const int tid = threadIdx.x, wave = tid >> 6, lane = tid & 63;
    const int lr = lane & 15, lg = lane >> 4;
    const int wm = wave & 1, wn = wave >> 1;

    __shared__ short As[128][68];
    __shared__ short Bs[128][68];
    f32x4 acc[4][4] = {};

    for (int ks = 0; ks < 5; ++ks) {
        __syncthreads();
        for (int u = 0; u < 4; ++u) {
            int idx = u * 256 + tid;
            int rr = idx >> 3, c8 = idx & 7;
            *reinterpret_cast<bf16x8*>(&As[rr][c8 * 8]) =
                *reinterpret_cast<const bf16x8*>(Xb + (mt0 + rr) * xrs + ks * xcs + c8 * 8);
            *reinterpret_cast<bf16x8*>(&Bs[rr][c8 * 8]) =
                *reinterpret_cast<const bf16x8*>(WvT + (size_t)(nt0 + rr) * 320 + ks * 64 + c8 * 8);
        }
        __syncthreads();
        #pragma unroll
        for (int kk = 0; kk < 2; ++kk) {
            bf16x8 af[4], bfv[4];
            #pragma unroll
            for (int f = 0; f < 4; ++f)
                af[f] = *reinterpret_cast<const bf16x8*>(&As[wm * 64 + f * 16 + lr][kk * 32 + lg * 8]);
            #pragma unroll
            for (int f = 0; f < 4; ++f)
                bfv[f] = *reinterpret_cast<const bf16x8*>(&Bs[wn * 64 + f * 16 + lr][kk * 32 + lg * 8]);
            #pragma unroll
            for (int i = 0; i < 4; ++i)
                #pragma unroll
                for (int j = 0; j < 4; ++j)
                    acc[i][j] = __builtin_amdgcn_mfma_f32_16x16x32_bf16(af[i], bfv[j], acc[i][j], 0, 0, 0);
        }
    }
    #pragma unroll
    for (int i = 0; i < 4; ++i)
        #pragma unroll
        for (int j = 0; j < 4; ++j)
            #pragma unroll
            for (int r = 0; r < 4; ++r)
                xv[(mt0 + wm * 64 + i * 16 + lg * 4 + r) * 256 + nt0 + wn * 64 + j * 16 + lr]
                    = f2b(acc[i][j][r]);
}

// ---------------------------------------------------------------------------
// qsc: q-GEMM (M=160, N=160 half-head chunk, K=320, BK=64, glds staging)
// + partial scores atomicAdd into ws. grid (200, 16, 2), 256 thr, 4 waves.
// LDS 53.1 KB -> 3 blocks/CU.
// ---------------------------------------------------------------------------
__global__ __launch_bounds__(256, 3) void qsc(
    const short* __restrict__ Xb,    // [32000][5][72]
    const short* __restrict__ WqT,   // [5120][5][72]
    float*       __restrict__ sco)   // [1600][16][20][20] f32 (pre-zeroed)
{
    const int g = blockIdx.x;        // 160-row chunk (8 bs)
    const int n = blockIdx.y;        // head
    const int h = blockIdx.z;        // q-col half: [160h, 160h+160)
    const int tid = threadIdx.x, wave = tid >> 6, lane = tid & 63;
    const int lr = lane & 15, lg = lane >> 4;
    const int wm = wave >> 1, wn = wave & 1;
    const size_t row0 = (size_t)g * 160;

    // A stage: segs 0..1439 (shorts 0..11519); B stage: segs 1440..2879
    // (shorts 11520..23039). glds overflow segs 2880..3071 land < 26560. 
    // qsm [160][166] (= 26560 shorts) aliases the whole array after the loop.
    __shared__ short lds[26560];

    // precompute 12 glds source pointers (seg s = i*256 + tid)
    const short* gp[12];
    #pragma unroll
    for (int i = 0; i < 12; ++i) {
        const int s = i * 256 + tid;
        if (s < 1440) {
            gp[i] = Xb + (row0 + s / 9) * 360 + (s % 9) * 8;
        } else if (s < 2880) {
            const int s2 = s - 1440;
            gp[i] = WqT + (size_t)(n * 320 + h * 160 + s2 / 9) * 360 + (s2 % 9) * 8;
        } else {
            gp[i] = Xb;   // unused (guarded)
        }
    }

    // ---- q-GEMM K-loop: 5 steps of BK=64, single LDS buffer + glds ----
    f32x4 acc[5][5] = {};
    for (int ks = 0; ks < 5; ++ks) {
        __syncthreads();                      // LDS free
        #pragma unroll
        for (int i = 0; i < 11; ++i)
            gload16(gp[i] + ks * 72, lds + (size_t)(i * 256 + (tid & 448)) * 8);
        if (tid < 64)
            gload16(gp[11] + ks * 72, lds + (size_t)2816 * 8);
        __syncthreads();                      // LDS filled (vmcnt drained)
        #pragma unroll
        for (int sub = 0; sub < 2; ++sub) {
            bf16x8 af[5], bfr[5];
            #pragma unroll
            for (int i = 0; i < 5; ++i)
                af[i] = *reinterpret_cast<const bf16x8*>(
                    lds + (wm * 80 + i * 16 + lr) * 72 + sub * 32 + lg * 8);
            #pragma unroll
            for (int j = 0; j < 5; ++j)
                bfr[j] = *reinterpret_cast<const bf16x8*>(
                    lds + 11520 + (wn * 80 + j * 16 + lr) * 72 + sub * 32 + lg * 8);
            #pragma unroll
            for (int i = 0; i < 5; ++i)
                #pragma unroll
                for (int j = 0; j < 5; ++j)
                    acc[i][j] = __builtin_amdgcn_mfma_f32_16x16x32_bf16(af[i], bfr[j], acc[i][j], 0, 0, 0);
        }
    }
    __syncthreads();   // all staging reads done -> safe to overwrite with qsm

    // ---- acc -> qsm [160][166] (local cols 0..159 of the h-chunk) ----
    #pragma unroll
    for (int i = 0; i < 5; ++i)
        #pragma unroll
        for (int j = 0; j < 5; ++j)
            #pragma unroll
            for (int r = 0; r < 4; ++r)
                lds[(wm * 80 + i * 16 + lg * 4 + r) * 166 + wn * 80 + j * 16 + lr]
                    = f2b(acc[i][j][r]);
    __syncthreads();

    // ---- partial scores: wave handles 2 bs; s += q_chunk . x_chunk^T ----
    const float scl = 0.057735026918962584f;  // 1/sqrt(300)
    #pragma unroll
    for (int bb = 0; bb < 2; ++bb) {
        const int b = wave * 2 + bb;
        const int rA0 = b * 20 + lr;
        int rA1 = b * 20 + 16 + lr; if (rA1 > 159) rA1 = 159;
        const size_t xr0 = row0 + rA0;
        const size_t xr1 = row0 + rA1;

        f32x4 s[2][2] = {};
        #pragma unroll
        for (int sub = 0; sub < 5; ++sub) {
            const int gc = h * 160 + sub * 32 + lg * 8;
            const int go = (gc >> 6) * 72 + (gc & 63);
            bf16x8 bx0 = *reinterpret_cast<const bf16x8*>(Xb + xr0 * 360 + go);
            bf16x8 bx1 = *reinterpret_cast<const bf16x8*>(Xb + xr1 * 360 + go);
            const int ko = sub * 32 + lg * 8;
            bf16x8 a0 = *reinterpret_cast<const bf16x8*>(lds + rA0 * 166 + ko);
            bf16x8 a1 = *reinterpret_cast<const bf16x8*>(lds + rA1 * 166 + ko);
            s[0][0] = __builtin_amdgcn_mfma_f32_16x16x32_bf16(a0, bx0, s[0][0], 0, 0, 0);
            s[0][1] = __builtin_amdgcn_mfma_f32_16x16x32_bf16(a0, bx1, s[0][1], 0, 0, 0);
            s[1][0] = __builtin_amdgcn_mfma_f32_16x16x32_bf16(a1, bx0, s[1][0], 0, 0, 0);
            s[1][1] = __builtin_amdgcn_mfma_f32_16x16x32_bf16(a1, bx1, s[1][1], 0, 0, 0);
        }
        const size_t bs = (size_t)g * 8 + b;
        float* sb = sco + (bs * 16 + n) * 400;
        #pragma unroll
        for (int mt = 0; mt < 2; ++mt)
            #pragma unroll
            for (int nt = 0; nt < 2; ++nt)
                #pragma unroll
                for (int r = 0; r < 4; ++r) {
                    const int row = mt * 16 + lg * 4 + r;
                    const int col = nt * 16 + lr;
                    if (row < LL && col < LL)
                        atomicAdd(sb + row * 20 + col, s[mt][nt][r] * scl);
                }
    }
}

// ---------------------------------------------------------------------------
// smv: softmax over scores + v = attn*xv. grid 1600, 256 thr, 4 waves.
// ---------------------------------------------------------------------------
__global__ __launch_bounds__(256) void smv(
    const float* __restrict__ sco,   // [1600][16][20][20]
    const short* __restrict__ xv,    // [32000][256]
    float*       __restrict__ out1)  // [32000][256]
{
    const int bs = blockIdx.x;
    const int tid = threadIdx.x, wave = tid >> 6, lane = tid & 63;
    const int lr = lane & 15, lg = lane >> 4;

    __shared__ float scf[6400];        // [16][20][20]
    __shared__ short atb[16 * 32 * 34];

    for (int i = tid; i < 8704; i += 256) reinterpret_cast<int*>(atb)[i] = 0;
    for (int i = tid; i < 6400; i += 256) scf[i] = sco[(size_t)bs * 6400 + i];
    __syncthreads();

    for (int t = tid; t < 320; t += 256) {
        const int n = t / 20, row = t % 20;
        const float* sr = scf + n * 400 + row * 20;
        float mx = -1e30f;
        #pragma unroll
        for (int m = 0; m < LL; ++m) mx = fmaxf(mx, sr[m]);
        float ev[LL], sum = 0.f;
        #pragma unroll
        for (int m = 0; m < LL; ++m) { ev[m] = __expf(sr[m] - mx); sum += ev[m]; }
        const float inv = 1.f / sum;
        short* ar = atb + (n * 32 + row) * 34;
        #pragma unroll
        for (int m = 0; m < LL; ++m) ar[m] = f2b(ev[m] * inv);
    }
    __syncthreads();

    // v: wave w handles heads 4w..4w+3
    for (int k = 0; k < 4; ++k) {
        const int n = wave * 4 + k;
        bf16x8 bv;
        #pragma unroll
        for (int j = 0; j < 8; ++j) {
            int m = lg * 8 + j; if (m > 19) m = 19;
            bv[j] = xv[((size_t)bs * 20 + m) * 256 + n * 16 + lr];
        }
        bf16x8 va0 = *reinterpret_cast<const bf16x8*>(atb + (n * 32 + lr) * 34 + lg * 8);
        bf16x8 va1 = *reinterpret_cast<const bf16x8*>(atb + (n * 32 + 16 + lr) * 34 + lg * 8);
        f32x4 z = {0.f, 0.f, 0.f, 0.f};
        f32x4 v0 = __builtin_amdgcn_mfma_f32_16x16x32_bf16(va0, bv, z, 0, 0, 0);
        f32x4 v1 = __builtin_amdgcn_mfma_f32_16x16x32_bf16(va1, bv, z, 0, 0, 0);
        #pragma unroll
        for (int r = 0; r < 4; ++r) {
            out1[((size_t)bs * 20 + lg * 4 + r) * 256 + n * 16 + lr] = v0[r];
            const int r1 = 16 + lg * 4 + r;
            if (r1 < LL)
                out1[((size_t)bs * 20 + r1) * 256 + n * 16 + lr] = v1[r];
        }
    }
}

// ---------------------------------------------------------------------------
// Pool (unchanged, proven)
// ---------------------------------------------------------------------------
__global__ __launch_bounds__(256) void nrms_pool_mfma(
    const float* __restrict__ out1,
    const short* __restrict__ kwb,
    const float* __restrict__ keyB,
    const float* __restrict__ query,
    float*       __restrict__ out2)
{
    const int bs   = blockIdx.x;
    const int tid  = threadIdx.x;
    const int wave = tid >> 6;
    const int lane = tid & 63;
    const int lr   = lane & 15;
    const int lg   = lane >> 4;

    __shared__ float mh[LL][257];
    __shared__ short mhb[32][264];
    __shared__ float s2p[32];

    for (int i = tid; i < 12 * 128; i += 256) {
        const int r = 20 + i / 128, c = (i % 128) * 2;
        *reinterpret_cast<int*>(&mhb[r][c]) = 0;
    }
    if (tid < 32) s2p[tid] = 0.f;

    for (int idx = tid; idx < LL * 64; idx += 256) {
        const int l = idx >> 6, h4 = (idx & 63) * 4;
        const float4 v = *reinterpret_cast<const float4*>(out1 + ((size_t)bs * LL + l) * HID + h4);
        mh[l][h4] = v.x; mh[l][h4 + 1] = v.y; mh[l][h4 + 2] = v.z; mh[l][h4 + 3] = v.w;
        mhb[l][h4] = f2b(v.x); mhb[l][h4 + 1] = f2b(v.y);
        mhb[l][h4 + 2] = f2b(v.z); mhb[l][h4 + 3] = f2b(v.w);
    }
    __syncthreads();

    for (int t = wave; t < 26; t += 4) {
        const int mt = t & 1, nt = t >> 1;
        f32x4 acc = {0.f, 0.f, 0.f, 0.f};
        const short* ap = &mhb[mt * 16 + lr][lg * 8];
        const short* bp = kwb + (nt * 16 + lr) * 256 + lg * 8;
        #pragma unroll
        for (int k = 0; k < 8; ++k) {
            bf16x8 a = *reinterpret_cast<const bf16x8*>(ap + k * 32);
            bf16x8 b = *reinterpret_cast<const bf16x8*>(bp + k * 32);
            acc = __builtin_amdgcn_mfma_f32_16x16x32_bf16(a, b, acc, 0, 0, 0);
        }
        const int d = nt * 16 + lr;
        const float qd = (d < QD) ? query[d] : 0.f;
        const float kb = (d < QD) ? keyB[d] : 0.f;
        float vals[4];
        #pragma unroll
        for (int r = 0; r < 4; ++r) vals[r] = qd * ftanh(acc[r] + kb);
        #pragma unroll
        for (int off = 1; off < 16; off <<= 1) {
            #pragma unroll
            for (int r = 0; r < 4; ++r) vals[r] += __shfl_xor(vals[r], off);
        }
        if (lr == 0) {
            #pragma unroll
            for (int r = 0; r < 4; ++r)
                atomicAdd(&s2p[mt * 16 + lg * 4 + r], vals[r]);
        }
    }
    __syncthreads();

    if (tid == 0) {
        float mx = -1e30f;
        #pragma unroll
        for (int l = 0; l < LL; ++l) mx = fmaxf(mx, s2p[l] * 0.07071067811865475f);
        float sum = 0.f;
        float e[LL];
        #pragma unroll
        for (int l = 0; l < LL; ++l) { e[l] = __expf(s2p[l] * 0.07071067811865475f - mx); sum += e[l]; }
        const float inv = 1.f / sum;
        #pragma unroll
        for (int l = 0; l < LL; ++l) s2p[l] = e[l] * inv;
    }
    __syncthreads();

    {
        const int h = tid;
        float acc = 0.f;
        #pragma unroll
        for (int l = 0; l < LL; ++l) acc = fmaf(s2p[l], mh[l][h], acc);
        out2[(size_t)bs * HID + h] = acc;
    }
}

// ===========================================================================
// MIDDLE TIER (round-8 path, ~40.4 MB ws): linear layouts + reg-staged qattn
// ===========================================================================

__global__ void build_xb_lin(const int* __restrict__ news, const float* __restrict__ emb,
                             short* __restrict__ Xb) {
    int idx = blockIdx.x * 256 + threadIdx.x;
    if (idx >= 32000 * 80) return;
    int i = idx / 80, e4 = (idx % 80) * 4;
    short4 o;
    if (e4 < 300) {
        const float4 v = *reinterpret_cast<const float4*>(emb + (size_t)news[i] * EE + e4);
        o.x = f2b(v.x); o.y = f2b(v.y); o.z = f2b(v.z); o.w = f2b(v.w);
    } else if (e4 == 300) {
        o.x = (short)0x3F80; o.y = 0; o.z = 0; o.w = 0;
    } else {
        o.x = o.y = o.z = o.w = 0;
    }
    *reinterpret_cast<short4*>(Xb + (size_t)i * 320 + e4) = o;
}

__global__ __launch_bounds__(1024) void build_wqt_lin(
    const float* __restrict__ qW, const float* __restrict__ qB, short* __restrict__ WqT)
{
    __shared__ float t[32][33];
    const int n = blockIdx.z;
    const int e0 = blockIdx.x * 32, f0 = blockIdx.y * 32;
    const int tx = threadIdx.x, ty = threadIdx.y;
    const int e = e0 + ty, f = f0 + tx;
    t[ty][tx] = (e < EE && f < EE) ? qW[((size_t)n * EE + e) * EE + f] : 0.f;
    __syncthreads();
    const int fo = f0 + ty, eo = e0 + tx;
    float val;
    if (fo >= EE)      val = 0.f;
    else if (eo < EE)  val = t[tx][ty];
    else if (eo == EE) val = qB[n * EE + fo];
    else               val = 0.f;
    WqT[((size_t)n * 320 + fo) * 320 + eo] = f2b(val);
}

#define QGEMM_COMPUTE                                                                        \
    {                                                                                        \
        bf16x8 af[5], bfr[5];                                                                \
        _Pragma("unroll")                                                                    \
        for (int i = 0; i < 5; ++i)                                                          \
            af[i] = *reinterpret_cast<const bf16x8*>(&Asg[wm * 80 + i * 16 + lr][lg * 8]);   \
        _Pragma("unroll")                                                                    \
        for (int j = 0; j < 5; ++j)                                                          \
            bfr[j] = *reinterpret_cast<const bf16x8*>(&Bsg[wn * 80 + j * 16 + lr][lg * 8]);  \
        _Pragma("unroll")                                                                    \
        for (int i = 0; i < 5; ++i)                                                          \
            _Pragma("unroll")                                                                \
            for (int j = 0; j < 5; ++j)                                                      \
                acc[i][j] = __builtin_amdgcn_mfma_f32_16x16x32_bf16(af[i], bfr[j], acc[i][j], 0, 0, 0); \
    }

__global__ __launch_bounds__(512, 2) void qattn_mid(
    const short* __restrict__ Xb,
    const short* __restrict__ WqT,
    const short* __restrict__ xv,
    float*       __restrict__ out1)
{
    const int g = blockIdx.x;
    const int n = blockIdx.y;
    const int tid = threadIdx.x, wave = tid >> 6, lane = tid & 63;
    const int lr = lane & 15, lg = lane >> 4;
    const int wm = wave >> 2, wn = wave & 3;
    const size_t row0 = (size_t)g * 160;

    __shared__ short qs[160][328];
    __shared__ short Asg[160][36];
    __shared__ short Bsg[320][36];
    __shared__ short atw[8][32][34];

    for (int i = tid; i < 4352; i += 512) reinterpret_cast<int*>(atw)[i] = 0;

    const short* wh = WqT + (size_t)n * 320 * 320;
    const bool isA = tid < 160;
    const bool stg = tid < 480;
    const short* gsrc = isA ? (Xb + (row0 + tid) * 320)
                            : (wh + (size_t)(stg ? tid - 160 : 0) * 320);
    short* ldst = isA ? &Asg[tid][0] : &Bsg[stg ? tid - 160 : 0][0];

    bf16x8 sA0, sA1, sA2, sA3, sB0, sB1, sB2, sB3;
    if (stg) {
        sA0 = *reinterpret_cast<const bf16x8*>(gsrc);
        sA1 = *reinterpret_cast<const bf16x8*>(gsrc + 8);
        sA2 = *reinterpret_cast<const bf16x8*>(gsrc + 16);
        sA3 = *reinterpret_cast<const bf16x8*>(gsrc + 24);
        sB0 = *reinterpret_cast<const bf16x8*>(gsrc + 32);
        sB1 = *reinterpret_cast<const bf16x8*>(gsrc + 40);
        sB2 = *reinterpret_cast<const bf16x8*>(gsrc + 48);
        sB3 = *reinterpret_cast<const bf16x8*>(gsrc + 56);
    }

    bf16x8 bv;
    {
        const int b = wave;
        #pragma unroll
        for (int j = 0; j < 8; ++j) {
            int m = lg * 8 + j; if (m > 19) m = 19;
            bv[j] = xv[(row0 + b * 20 + m) * 256 + n * 16 + lr];
        }
    }

    f32x4 acc[5][5] = {};
    #pragma unroll
    for (int kp = 0; kp < 5; ++kp) {
        __syncthreads();
        if (stg) {
            *reinterpret_cast<bf16x8*>(ldst)      = sA0;
            *reinterpret_cast<bf16x8*>(ldst + 8)  = sA1;
            *reinterpret_cast<bf16x8*>(ldst + 16) = sA2;
            *reinterpret_cast<bf16x8*>(ldst + 24) = sA3;
        }
        __syncthreads();
        if (kp < 4 && stg) {
            const short* s = gsrc + (kp * 2 + 2) * 32;
            sA0 = *reinterpret_cast<const bf16x8*>(s);
            sA1 = *reinterpret_cast<const bf16x8*>(s + 8);
            sA2 = *reinterpret_cast<const bf16x8*>(s + 16);
            sA3 = *reinterpret_cast<const bf16x8*>(s + 24);
        }
        QGEMM_COMPUTE;
        __syncthreads();
        if (stg) {
            *reinterpret_cast<bf16x8*>(ldst)      = sB0;
            *reinterpret_cast<bf16x8*>(ldst + 8)  = sB1;
            *reinterpret_cast<bf16x8*>(ldst + 16) = sB2;
            *reinterpret_cast<bf16x8*>(ldst + 24) = sB3;
        }
        __syncthreads();
        if (kp < 4 && stg) {
            const short* s = gsrc + (kp * 2 + 3) * 32;
            sB0 = *reinterpret_cast<const bf16x8*>(s);
            sB1 = *reinterpret_cast<const bf16x8*>(s + 8);
            sB2 = *reinterpret_cast<const bf16x8*>(s + 16);
            sB3 = *reinterpret_cast<const bf16x8*>(s + 24);
        }
        QGEMM_COMPUTE;
    }

    const int b = wave;
    const int rA0 = b * 20 + lr;
    int rA1 = b * 20 + 16 + lr; if (rA1 > 159) rA1 = 159;
    const size_t rB0g = row0 + b * 20 + lr;
    size_t rB1g = row0 + rA1;

    bf16x8 xpre0[10], xpre1[10];
    #pragma unroll
    for (int ks = 0; ks < 10; ++ks) {
        xpre0[ks] = *reinterpret_cast<const bf16x8*>(Xb + rB0g * 320 + ks * 32 + lg * 8);
        xpre1[ks] = *reinterpret_cast<const bf16x8*>(Xb + rB1g * 320 + ks * 32 + lg * 8);
    }

    #pragma unroll
    for (int i = 0; i < 5; ++i)
        #pragma unroll
        for (int j = 0; j < 5; ++j)
            #pragma unroll
            for (int r = 0; r < 4; ++r)
                qs[wm * 80 + i * 16 + lg * 4 + r][wn * 80 + j * 16 + lr] = f2b(acc[i][j][r]);
    __syncthreads();

    {
        f32x4 s[2][2] = {};
        #pragma unroll
        for (int ks = 0; ks < 10; ++ks) {
            const int kc = ks * 32 + lg * 8;
            bf16x8 a0 = *reinterpret_cast<const bf16x8*>(&qs[rA0][kc]);
            bf16x8 a1 = *reinterpret_cast<const bf16x8*>(&qs[rA1][kc]);
            s[0][0] = __builtin_amdgcn_mfma_f32_16x16x32_bf16(a0, xpre0[ks], s[0][0], 0, 0, 0);
            s[0][1] = __builtin_amdgcn_mfma_f32_16x16x32_bf16(a0, xpre1[ks], s[0][1], 0, 0, 0);
            s[1][0] = __builtin_amdgcn_mfma_f32_16x16x32_bf16(a1, xpre0[ks], s[1][0], 0, 0, 0);
            s[1][1] = __builtin_amdgcn_mfma_f32_16x16x32_bf16(a1, xpre1[ks], s[1][1], 0, 0, 0);
        }

        const float scl = 0.057735026918962584f;
        #pragma unroll
        for (int mts = 0; mts < 2; ++mts) {
            #pragma unroll
            for (int r = 0; r < 4; ++r) {
                float v0 = s[mts][0][r] * scl;
                float v1 = s[mts][1][r] * scl;
                float mx = (lr < 4) ? fmaxf(v0, v1) : v0;
                mx = fmaxf(mx, __shfl_xor(mx, 1));
                mx = fmaxf(mx, __shfl_xor(mx, 2));
                mx = fmaxf(mx, __shfl_xor(mx, 4));
                mx = fmaxf(mx, __shfl_xor(mx, 8));
                float e0 = __expf(v0 - mx);
                float e1 = (lr < 4) ? __expf(v1 - mx) : 0.f;
                float sm = e0 + e1;
                sm += __shfl_xor(sm, 1);
                sm += __shfl_xor(sm, 2);
                sm += __shfl_xor(sm, 4);
                sm += __shfl_xor(sm, 8);
                const float inv = 1.f / sm;
                const int row = mts * 16 + lg * 4 + r;
                if (row < LL) {
                    atw[b][row][lr]      = f2b(e0 * inv);
                    atw[b][row][16 + lr] = f2b(e1 * inv);
                }
            }
        }
    }
    __syncthreads();

    {
        bf16x8 va0 = *reinterpret_cast<const bf16x8*>(&atw[b][lr][lg * 8]);
        bf16x8 va1 = *reinterpret_cast<const bf16x8*>(&atw[b][16 + lr][lg * 8]);
        f32x4 z = {0.f, 0.f, 0.f, 0.f};
        f32x4 v0 = __builtin_amdgcn_mfma_f32_16x16x32_bf16(va0, bv, z, 0, 0, 0);
        f32x4 v1 = __builtin_amdgcn_mfma_f32_16x16x32_bf16(va1, bv, z, 0, 0, 0);
        #pragma unroll
        for (int r = 0; r < 4; ++r) {
            const int rowl = lg * 4 + r;
            out1[(row0 + b * 20 + rowl) * 256 + n * 16 + lr] = v0[r];
            const int rowl1 = 16 + lg * 4 + r;
            if (rowl1 < LL)
                out1[(row0 + b * 20 + rowl1) * 256 + n * 16 + lr] = v1[r];
        }
    }
}

// ===========================================================================
// FALLBACK (round-3)
// ===========================================================================

#define XP 330
#define TP 42
#define AP 34

__global__ __launch_bounds__(1024) void transpose_qw(
    const float* __restrict__ qW, short* __restrict__ wqt)
{
    __shared__ float t[32][33];
    const int n = blockIdx.z;
    const int e0 = blockIdx.x * 32, f0 = blockIdx.y * 32;
    const int tx = threadIdx.x, ty = threadIdx.y;
    const int e = e0 + ty, f = f0 + tx;
    t[ty][tx] = (e < EE && f < EE) ? qW[(size_t)n * EE * EE + e * EE + f] : 0.f;
    __syncthreads();
    const int fo = f0 + ty, eo = e0 + tx;
    if (fo < 304)
        wqt[(size_t)n * 304 * 320 + fo * 320 + eo] = f2b(t[tx][ty]);
}

__global__ void conv_vw(const float* __restrict__ vW, short* __restrict__ wvt) {
    int idx = blockIdx.x * 256 + threadIdx.x;
    if (idx >= NH * VD * 320) return;
    int e = idx % 320;
    int v = (idx / 320) % VD;
    int n = idx / (320 * VD);
    wvt[idx] = (e < EE) ? f2b(vW[(size_t)n * EE * VD + e * VD + v]) : (short)0;
}

__global__ __launch_bounds__(512) void nrms_attn_mfma(
    const int*   __restrict__ news,
    const float* __restrict__ emb,
    const short* __restrict__ wqt,
    const float* __restrict__ qB,
    const short* __restrict__ wvt,
    const float* __restrict__ vB,
    float*       __restrict__ out1)
{
    const int bs   = blockIdx.x;
    const int tid  = threadIdx.x;
    const int wave = tid >> 6;
    const int lane = tid & 63;
    const int lr   = lane & 15;
    const int lg   = lane >> 4;

    __shared__ short xs[32][XP];
    __shared__ short xT[320][TP];
    __shared__ short qs[32][XP];
    __shared__ float sc[32][33];
    __shared__ short at[32][AP];

    {
        int* z = (int*)&xs[0][0];
        for (int i = tid; i < 32 * XP / 2; i += 512) z[i] = 0;
        z = (int*)&qs[0][0];
        for (int i = tid; i < 32 * XP / 2; i += 512) z[i] = 0;
        z = (int*)&xT[0][0];
        for (int i = tid; i < 320 * TP / 2; i += 512) z[i] = 0;
    }
    __syncthreads();

    for (int idx = tid; idx < LL * 75; idx += 512) {
        const int l = idx / 75, e4 = (idx % 75) * 4;
        const int row = news[bs * LL + l];
        const float4 v = *reinterpret_cast<const float4*>(emb + (size_t)row * EE + e4);
        const short b0 = f2b(v.x), b1 = f2b(v.y), b2 = f2b(v.z), b3 = f2b(v.w);
        xs[l][e4] = b0; xs[l][e4 + 1] = b1; xs[l][e4 + 2] = b2; xs[l][e4 + 3] = b3;
        xT[e4][l] = b0; xT[e4 + 1][l] = b1; xT[e4 + 2][l] = b2; xT[e4 + 3][l] = b3;
    }
    __syncthreads();

    for (int n = 0; n < NH; ++n) {
        const short* wq = wqt + (size_t)n * 304 * 320;

        for (int p = wave; p < 19; p += 8) {
            f32x4 acc0 = {0.f, 0.f, 0.f, 0.f};
            f32x4 acc1 = {0.f, 0.f, 0.f, 0.f};
            const short* a0p = &xs[lr][lg * 8];
            const short* a1p = &xs[16 + lr][lg * 8];
            const short* bp  = wq + (p * 16 + lr) * 320 + lg * 8;
            #pragma unroll
            for (int k = 0; k < 10; ++k) {
                bf16x8 b  = *reinterpret_cast<const bf16x8*>(bp + k * 32);
                bf16x8 a0 = *reinterpret_cast<const bf16x8*>(a0p + k * 32);
                bf16x8 a1 = *reinterpret_cast<const bf16x8*>(a1p + k * 32);
                acc0 = __builtin_amdgcn_mfma_f32_16x16x32_bf16(a0, b, acc0, 0, 0, 0);
                acc1 = __builtin_amdgcn_mfma_f32_16x16x32_bf16(a1, b, acc1, 0, 0, 0);
            }
            const int col = p * 16 + lr;
            const float bias = (col < EE) ? qB[n * EE + col] : 0.f;
            #pragma unroll
            for (int r = 0; r < 4; ++r) {
                qs[lg * 4 + r][col]      = f2b(acc0[r] + bias);
                qs[16 + lg * 4 + r][col] = f2b(acc1[r] + bias);
            }
        }
        __syncthreads();

        if (wave < 4) {
            const int mt = wave & 1, nt = wave >> 1;
            f32x4 acc = {0.f, 0.f, 0.f, 0.f};
            const short* ap = &qs[mt * 16 + lr][lg * 8];
            const short* bp = &xs[nt * 16 + lr][lg * 8];
            #pragma unroll
            for (int k = 0; k < 10; ++k) {
                bf16x8 a = *reinterpret_cast<const bf16x8*>(ap + k * 32);
                bf16x8 b = *reinterpret_cast<const bf16x8*>(bp + k * 32);
                acc = __builtin_amdgcn_mfma_f32_16x16x32_bf16(a, b, acc, 0, 0, 0);
            }
            #pragma unroll
            for (int r = 0; r < 4; ++r)
                sc[mt * 16 + lg * 4 + r][nt * 16 + lr] = acc[r] * 0.057735026918962584f;
        }
        __syncthreads();

        if (tid < LL) {
            float mx = -1e30f;
            #pragma unroll
            for (int m = 0; m < LL; ++m) mx = fmaxf(mx, sc[tid][m]);
            float ev[LL], sum = 0.f;
            #pragma unroll
            for (int m = 0; m < LL; ++m) { ev[m] = __expf(sc[tid][m] - mx); sum += ev[m]; }
            const float inv = 1.f / sum;
            #pragma unroll
            for (int m = 0; m < LL; ++m) at[tid][m] = f2b(ev[m] * inv);
            #pragma unroll
            for (int m = LL; m < 32; ++m) at[tid][m] = 0;
        } else if (tid < 32) {
            int* zr = (int*)&at[tid][0];
            #pragma unroll
            for (int m = 0; m < 16; ++m) zr[m] = 0;
        }
        __syncthreads();

        for (int p = wave; p < 19; p += 8) {
            bf16x8 b  = *reinterpret_cast<const bf16x8*>(&xT[p * 16 + lr][lg * 8]);
            bf16x8 a0 = *reinterpret_cast<const bf16x8*>(&at[lr][lg * 8]);
            bf16x8 a1 = *reinterpret_cast<const bf16x8*>(&at[16 + lr][lg * 8]);
            f32x4 z = {0.f, 0.f, 0.f, 0.f};
            f32x4 c0 = __builtin_amdgcn_mfma_f32_16x16x32_bf16(a0, b, z, 0, 0, 0);
            f32x4 c1 = __builtin_amdgcn_mfma_f32_16x16x32_bf16(a1, b, z, 0, 0, 0);
            const int col = p * 16 + lr;
            #pragma unroll
            for (int r = 0; r < 4; ++r) {
                qs[lg * 4 + r][col]      = f2b(c0[r]);
                qs[16 + lg * 4 + r][col] = f2b(c1[r]);
            }
        }
        __syncthreads();

        if (wave < 2) {
            const int mt = wave;
            f32x4 acc = {0.f, 0.f, 0.f, 0.f};
            const short* ap = &qs[mt * 16 + lr][lg * 8];
            const short* bp = wvt + (size_t)n * VD * 320 + lr * 320 + lg * 8;
            #pragma unroll
            for (int k = 0; k < 10; ++k) {
                bf16x8 a = *reinterpret_cast<const bf16x8*>(ap + k * 32);
                bf16x8 b = *reinterpret_cast<const bf16x8*>(bp + k * 32);
                acc = __builtin_amdgcn_mfma_f32_16x16x32_bf16(a, b, acc, 0, 0, 0);
            }
            #pragma unroll
            for (int r = 0; r < 4; ++r) {
                const int row = mt * 16 + lg * 4 + r;
                if (row < LL)
                    out1[((size_t)bs * LL + row) * HID + n * VD + lr] = acc[r] + vB[n * VD + lr];
            }
        }
        __syncthreads();
    }
}

// ===========================================================================

extern "C" void kernel_launch(void* const* d_in, const int* in_sizes, int n_in,
                              void* d_out, int out_size, void* d_ws, size_t ws_size,
                              hipStream_t stream) {
    const int*   news  = (const int*)d_in[0];
    const float* emb   = (const float*)d_in[1];
    const float* qW    = (const float*)d_in[2];
    const float* qB    = (const float*)d_in[3];
    const float* vW    = (const float*)d_in[4];
    const float* vB    = (const float*)d_in[5];
    const float* keyW  = (const float*)d_in[6];
    const float* keyB  = (const float*)d_in[7];
    const float* query = (const float*)d_in[8];

    float* out1 = (float*)d_out;            // news_embedding: 8192000 floats
    float* out2 = out1 + 8192000;           // news_repr: 409600 floats

    // new path sizes (shorts): Xb_c 11520000, WqT_c 1843200, WvT 81920,
    // xv 8192000, kwb 53248; then scores f32 10240000.
    const size_t SH2   = 11520000ull + 1843200 + 81920 + 8192000 + 53248;
    const size_t NEED2 = SH2 * 2 + 10240000ull * 4;            // 84,340,736
    const size_t NEED1 = (10240000ull + 1638400 + 81920 + 8192000 + 53248) * 2;

    if (ws_size >= NEED2) {
        short* Xb  = (short*)d_ws;
        short* WqT = Xb + 11520000;
        short* WvT = WqT + 1843200;
        short* xv  = WvT + 81920;
        short* kwb = xv + 8192000;
        float* sco = (float*)((short*)d_ws + SH2);

        hipLaunchKernelGGL(build_xb_c, dim3(5625), dim3(256), 0, stream, news, emb, Xb);
        hipLaunchKernelGGL(build_wqt_c, dim3(10, 10, 16), dim3(32, 32), 0, stream, qW, qB, WqT);
        hipLaunchKernelGGL(build_wvt, dim3(320), dim3(256), 0, stream, vW, vB, WvT);
        hipLaunchKernelGGL(conv_kw, dim3(208), dim3(256), 0, stream, keyW, kwb);
        hipMemsetAsync(sco, 0, 10240000ull * 4, stream);
        hipLaunchKernelGGL(gemm_xv, dim3(2, 250), dim3(256), 0, stream, Xb, WvT, xv, 360, 72);
        hipLaunchKernelGGL(qsc, dim3(200, 16, 2), dim3(256), 0, stream, Xb, WqT, sco);
        hipLaunchKernelGGL(smv, dim3(NBS), dim3(256), 0, stream, sco, xv, out1);
        hipLaunchKernelGGL(nrms_pool_mfma, dim3(NBS), dim3(256), 0, stream,
                           out1, kwb, keyB, query, out2);
    } else if (ws_size >= NEED1) {
        short* Xb  = (short*)d_ws;
        short* WqT = Xb + 10240000;
        short* WvT = WqT + 1638400;
        short* xv  = WvT + 81920;
        short* kwb = xv + 8192000;

        hipLaunchKernelGGL(build_xb_lin, dim3(10000), dim3(256), 0, stream, news, emb, Xb);
        hipLaunchKernelGGL(build_wqt_lin, dim3(10, 10, 16), dim3(32, 32), 0, stream, qW, qB, WqT);
        hipLaunchKernelGGL(build_wvt, dim3(320), dim3(256), 0, stream, vW, vB, WvT);
        hipLaunchKernelGGL(conv_kw, dim3(208), dim3(256), 0, stream, keyW, kwb);
        hipLaunchKernelGGL(gemm_xv, dim3(2, 250), dim3(256), 0, stream, Xb, WvT, xv, 320, 64);
        hipLaunchKernelGGL(qattn_mid, dim3(200, 16), dim3(512), 0, stream, Xb, WqT, xv, out1);
        hipLaunchKernelGGL(nrms_pool_mfma, dim3(NBS), dim3(256), 0, stream,
                           out1, kwb, keyB, query, out2);
    } else {
        short* wqt = (short*)d_ws;
        short* wvt = wqt + (size_t)NH * 304 * 320;
        short* kwb = wvt + (size_t)NH * VD * 320;

        hipLaunchKernelGGL(transpose_qw, dim3(10, 10, 16), dim3(32, 32), 0, stream, qW, wqt);
        hipLaunchKernelGGL(conv_vw, dim3(320), dim3(256), 0, stream, vW, wvt);
        hipLaunchKernelGGL(conv_kw, dim3(208), dim3(256), 0, stream, keyW, kwb);
        hipLaunchKernelGGL(nrms_attn_mfma, dim3(NBS), dim3(512), 0, stream,
                           news, emb, wqt, qB, wvt, vB, out1);
        hipLaunchKernelGGL(nrms_pool_mfma, dim3(NBS), dim3(256), 0, stream,
                           out1, kwb, keyB, query, out2);
    }
}

// Round 11
// 340.181 us; speedup vs baseline: 1.9369x; 1.4411x over previous
//
#include <hip/hip_runtime.h>
#include <math.h>

#define NBS 1600      // B*S
#define LL 20
#define EE 300
#define NH 16
#define VD 16
#define HID 256
#define QD 200

typedef short bf16x8 __attribute__((ext_vector_type(8)));
typedef float f32x4 __attribute__((ext_vector_type(4)));

__device__ __forceinline__ short f2b(float f) {
    union { float f; unsigned u; } c; c.f = f;
    unsigned r = (c.u + 0x7FFFu + ((c.u >> 16) & 1u)) >> 16;  // RNE
    return (short)r;
}

__device__ __forceinline__ float ftanh(float a) {
    a = fminf(fmaxf(a, -15.f), 15.f);
    float t = __expf(2.f * a);
    return (t - 1.f) / (t + 1.f);
}

__device__ __forceinline__ void gload16(const short* g, short* l) {
    __builtin_amdgcn_global_load_lds(
        (const __attribute__((address_space(1))) unsigned int*)g,
        (__attribute__((address_space(3))) unsigned int*)l, 16, 0, 0);
}

// ===========================================================================
// Build kernels (linear layouts)
// ===========================================================================

// news/emb -> Xb bf16 [32000][320]; col300 = 1.0 (bias channel), 301..319 = 0
__global__ void build_xb_lin(const int* __restrict__ news, const float* __restrict__ emb,
                             short* __restrict__ Xb) {
    int idx = blockIdx.x * 256 + threadIdx.x;
    if (idx >= 32000 * 80) return;
    int i = idx / 80, e4 = (idx % 80) * 4;
    short4 o;
    if (e4 < 300) {
        const float4 v = *reinterpret_cast<const float4*>(emb + (size_t)news[i] * EE + e4);
        o.x = f2b(v.x); o.y = f2b(v.y); o.z = f2b(v.z); o.w = f2b(v.w);
    } else if (e4 == 300) {
        o.x = (short)0x3F80; o.y = 0; o.z = 0; o.w = 0;
    } else {
        o.x = o.y = o.z = o.w = 0;
    }
    *reinterpret_cast<short4*>(Xb + (size_t)i * 320 + e4) = o;
}

// Wq [n][e][f] -> WqT bf16 [5120 rows = n*320+f][320 cols = e], col300 = qB
__global__ __launch_bounds__(1024) void build_wqt_lin(
    const float* __restrict__ qW, const float* __restrict__ qB, short* __restrict__ WqT)
{
    __shared__ float t[32][33];
    const int n = blockIdx.z;
    const int e0 = blockIdx.x * 32, f0 = blockIdx.y * 32;
    const int tx = threadIdx.x, ty = threadIdx.y;
    const int e = e0 + ty, f = f0 + tx;
    t[ty][tx] = (e < EE && f < EE) ? qW[((size_t)n * EE + e) * EE + f] : 0.f;
    __syncthreads();
    const int fo = f0 + ty, eo = e0 + tx;
    float val;
    if (fo >= EE)      val = 0.f;
    else if (eo < EE)  val = t[tx][ty];
    else if (eo == EE) val = qB[n * EE + fo];
    else               val = 0.f;
    WqT[((size_t)n * 320 + fo) * 320 + eo] = f2b(val);
}

// Wv [n][e][v] -> WvT bf16 [256][320], col300 = vB
__global__ void build_wvt(const float* __restrict__ vW, const float* __restrict__ vB,
                          short* __restrict__ WvT) {
    int idx = blockIdx.x * 256 + threadIdx.x;
    if (idx >= 256 * 320) return;
    int c = idx / 320, e = idx % 320;
    int n = c >> 4, vd = c & 15;
    float val = (e < EE) ? vW[((size_t)n * EE + e) * VD + vd]
                         : (e == EE ? vB[n * VD + vd] : 0.f);
    WvT[idx] = f2b(val);
}

// keyW [200][256] fp32 -> bf16 [208][256]
__global__ void conv_kw(const float* __restrict__ keyW, short* __restrict__ kwb) {
    int idx = blockIdx.x * 256 + threadIdx.x;
    if (idx >= 208 * 256) return;
    int d = idx >> 8;
    kwb[idx] = (d < QD) ? f2b(keyW[idx]) : (short)0;
}

// xv = Xb * WvT^T : [32000][256] bf16.  128x128 tile, 4 waves.
__global__ __launch_bounds__(256) void gemm_xv(
    const short* __restrict__ Xb, const short* __restrict__ WvT, short* __restrict__ xv)
{
    const int nt0 = blockIdx.x * 128;
    const size_t mt0 = (size_t)blockIdx.y * 128;
    const int tid = threadIdx.x, wave = tid >> 6, lane = tid & 63;
    const int lr = lane & 15, lg = lane >> 4;
    const int wm = wave & 1, wn = wave >> 1;

    __shared__ short As[128][68];
    __shared__ short Bs[128][68];
    f32x4 acc[4][4] = {};

    for (int ks = 0; ks < 5; ++ks) {
        __syncthreads();
        for (int u = 0; u < 4; ++u) {
            int idx = u * 256 + tid;
            int rr = idx >> 3, c8 = idx & 7;
            *reinterpret_cast<bf16x8*>(&As[rr][c8 * 8]) =
                *reinterpret_cast<const bf16x8*>(Xb + (mt0 + rr) * 320 + ks * 64 + c8 * 8);
            *reinterpret_cast<bf16x8*>(&Bs[rr][c8 * 8]) =
                *reinterpret_cast<const bf16x8*>(WvT + (size_t)(nt0 + rr) * 320 + ks * 64 + c8 * 8);
        }
        __syncthreads();
        #pragma unroll
        for (int kk = 0; kk < 2; ++kk) {
            bf16x8 af[4], bfv[4];
            #pragma unroll
            for (int f = 0; f < 4; ++f)
                af[f] = *reinterpret_cast<const bf16x8*>(&As[wm * 64 + f * 16 + lr][kk * 32 + lg * 8]);
            #pragma unroll
            for (int f = 0; f < 4; ++f)
                bfv[f] = *reinterpret_cast<const bf16x8*>(&Bs[wn * 64 + f * 16 + lr][kk * 32 + lg * 8]);
            #pragma unroll
            for (int i = 0; i < 4; ++i)
                #pragma unroll
                for (int j = 0; j < 4; ++j)
                    acc[i][j] = __builtin_amdgcn_mfma_f32_16x16x32_bf16(af[i], bfv[j], acc[i][j], 0, 0, 0);
        }
    }
    #pragma unroll
    for (int i = 0; i < 4; ++i)
        #pragma unroll
        for (int j = 0; j < 4; ++j)
            #pragma unroll
            for (int r = 0; r < 4; ++r)
                xv[(mt0 + wm * 64 + i * 16 + lg * 4 + r) * 256 + nt0 + wn * 64 + j * 16 + lr]
                    = f2b(acc[i][j][r]);
}

// ---------------------------------------------------------------------------
// gemm_q: m97-exact GEMM slab.  C[slabRows][5120] = Xb[slab] * WqT^T.
// 128x128 tile, 4 waves (64x64 each, 4x4 frags), BK=32, global_load_lds(16B),
// linear LDS A[128][32]+B[128][32] = 16 KB -> 4+ blocks/CU.
// ---------------------------------------------------------------------------
__global__ __launch_bounds__(256, 4) void gemm_q(
    const short* __restrict__ Xb,    // [32000][320]
    const short* __restrict__ WqT,   // [5120][320]
    short*       __restrict__ q,     // [slabRows][5120]
    int rowbase)
{
    const int nt0 = blockIdx.x * 128;
    const int mt0 = blockIdx.y * 128;
    const int tid = threadIdx.x, wave = tid >> 6, lane = tid & 63;
    const int lr = lane & 15, lg = lane >> 4;
    const int wm = wave & 1, wn = wave >> 1;

    __shared__ short sAB[8192];      // A @ [0,4096) shorts, B @ [4096,8192)

    const int rA = tid >> 2, c = tid & 3;   // seg: 4 segs of 16B per 32-col row
    const short* aS0 = Xb + (size_t)(rowbase + mt0 + rA) * 320 + c * 8;
    const short* aS1 = aS0 + (size_t)64 * 320;
    const short* bS0 = WqT + (size_t)(nt0 + rA) * 320 + c * 8;
    const short* bS1 = bS0 + (size_t)64 * 320;
    short* d0 = sAB + tid * 8;              // linear lane-contiguous glds dests
    short* d1 = sAB + (tid + 256) * 8;
    short* d2 = sAB + (tid + 512) * 8;
    short* d3 = sAB + (tid + 768) * 8;

    f32x4 acc[4][4] = {};
    for (int ks = 0; ks < 10; ++ks) {
        __syncthreads();                    // previous step's frag reads done
        const int ko = ks * 32;
        gload16(aS0 + ko, d0);
        gload16(aS1 + ko, d1);
        gload16(bS0 + ko, d2);
        gload16(bS1 + ko, d3);
        __syncthreads();                    // glds drained (vmcnt 0 at barrier)
        bf16x8 af[4], bfr[4];
        #pragma unroll
        for (int i = 0; i < 4; ++i)
            af[i] = *reinterpret_cast<const bf16x8*>(sAB + (wm * 64 + i * 16 + lr) * 32 + lg * 8);
        #pragma unroll
        for (int j = 0; j < 4; ++j)
            bfr[j] = *reinterpret_cast<const bf16x8*>(sAB + 4096 + (wn * 64 + j * 16 + lr) * 32 + lg * 8);
        #pragma unroll
        for (int i = 0; i < 4; ++i)
            #pragma unroll
            for (int j = 0; j < 4; ++j)
                acc[i][j] = __builtin_amdgcn_mfma_f32_16x16x32_bf16(af[i], bfr[j], acc[i][j], 0, 0, 0);
    }

    #pragma unroll
    for (int i = 0; i < 4; ++i)
        #pragma unroll
        for (int j = 0; j < 4; ++j)
            #pragma unroll
            for (int r = 0; r < 4; ++r)
                q[(size_t)(mt0 + wm * 64 + i * 16 + lg * 4 + r) * 5120
                  + nt0 + wn * 64 + j * 16 + lr] = f2b(acc[i][j][r]);
}

// ---------------------------------------------------------------------------
// sv: scores + softmax + v per slab.  grid = bscount*4 blocks, 256 thr,
// one head per wave (4 heads/block).  q from L3, x staged in LDS,
// no inner barriers (atw is wave-private).
// ---------------------------------------------------------------------------
__global__ __launch_bounds__(256, 3) void sv(
    const short* __restrict__ Xb,    // [32000][320]
    const short* __restrict__ q,     // [slabRows][5120]
    const short* __restrict__ xv,    // [32000][256]
    float*       __restrict__ out1,  // [32000][256]
    int bsbase)
{
    const int bs = bsbase + (blockIdx.x >> 2);
    const int hq = blockIdx.x & 3;
    const int tid = threadIdx.x, wave = tid >> 6, lane = tid & 63;
    const int lr = lane & 15, lg = lane >> 4;
    const int n = hq * 4 + wave;

    __shared__ short xs[20][328];        // stride 164 dw == 4 mod 32
    __shared__ short atw[4][32][34];     // per-wave attn scratch

    for (int i = tid; i < 2176; i += 256) reinterpret_cast<int*>(atw)[i] = 0;
    for (int idx = tid; idx < 800; idx += 256) {
        int l = idx / 40, c8 = idx % 40;
        *reinterpret_cast<bf16x8*>(&xs[l][c8 * 8]) =
            *reinterpret_cast<const bf16x8*>(Xb + ((size_t)bs * 20 + l) * 320 + c8 * 8);
    }
    __syncthreads();

    const short* qb = q + (size_t)(bs - bsbase) * 20 * 5120 + n * 320;
    int l1 = 16 + lr; if (l1 > 19) l1 = 19;

    f32x4 s[2][2] = {};
    #pragma unroll
    for (int ks = 0; ks < 10; ++ks) {
        const int ko = ks * 32 + lg * 8;
        bf16x8 a0 = *reinterpret_cast<const bf16x8*>(qb + (size_t)lr * 5120 + ko);
        bf16x8 a1 = *reinterpret_cast<const bf16x8*>(qb + (size_t)l1 * 5120 + ko);
        bf16x8 b0 = *reinterpret_cast<const bf16x8*>(&xs[lr][ko]);
        bf16x8 b1 = *reinterpret_cast<const bf16x8*>(&xs[l1][ko]);
        s[0][0] = __builtin_amdgcn_mfma_f32_16x16x32_bf16(a0, b0, s[0][0], 0, 0, 0);
        s[0][1] = __builtin_amdgcn_mfma_f32_16x16x32_bf16(a0, b1, s[0][1], 0, 0, 0);
        s[1][0] = __builtin_amdgcn_mfma_f32_16x16x32_bf16(a1, b0, s[1][0], 0, 0, 0);
        s[1][1] = __builtin_amdgcn_mfma_f32_16x16x32_bf16(a1, b1, s[1][1], 0, 0, 0);
    }

    const float scl = 0.057735026918962584f;  // 1/sqrt(300)
    #pragma unroll
    for (int mts = 0; mts < 2; ++mts) {
        #pragma unroll
        for (int r = 0; r < 4; ++r) {
            float v0 = s[mts][0][r] * scl;
            float v1 = s[mts][1][r] * scl;
            float mx = (lr < 4) ? fmaxf(v0, v1) : v0;
            mx = fmaxf(mx, __shfl_xor(mx, 1));
            mx = fmaxf(mx, __shfl_xor(mx, 2));
            mx = fmaxf(mx, __shfl_xor(mx, 4));
            mx = fmaxf(mx, __shfl_xor(mx, 8));
            float e0 = __expf(v0 - mx);
            float e1 = (lr < 4) ? __expf(v1 - mx) : 0.f;
            float sm = e0 + e1;
            sm += __shfl_xor(sm, 1);
            sm += __shfl_xor(sm, 2);
            sm += __shfl_xor(sm, 4);
            sm += __shfl_xor(sm, 8);
            const float inv = 1.f / sm;
            const int row = mts * 16 + lg * 4 + r;
            if (row < LL) {
                atw[wave][row][lr]      = f2b(e0 * inv);
                atw[wave][row][16 + lr] = f2b(e1 * inv);   // lr>=4 writes 0
            }
        }
    }
    // wave-private atw: ds-write -> ds-read ordering handled by lgkmcnt

    bf16x8 bv;
    #pragma unroll
    for (int j = 0; j < 8; ++j) {
        int m = lg * 8 + j; if (m > 19) m = 19;   // attn cols >=20 are zero
        bv[j] = xv[((size_t)bs * 20 + m) * 256 + n * 16 + lr];
    }
    bf16x8 va0 = *reinterpret_cast<const bf16x8*>(&atw[wave][lr][lg * 8]);
    bf16x8 va1 = *reinterpret_cast<const bf16x8*>(&atw[wave][16 + lr][lg * 8]);
    f32x4 z = {0.f, 0.f, 0.f, 0.f};
    f32x4 v0 = __builtin_amdgcn_mfma_f32_16x16x32_bf16(va0, bv, z, 0, 0, 0);
    f32x4 v1 = __builtin_amdgcn_mfma_f32_16x16x32_bf16(va1, bv, z, 0, 0, 0);
    #pragma unroll
    for (int r = 0; r < 4; ++r) {
        const int rowl = lg * 4 + r;
        out1[((size_t)bs * 20 + rowl) * 256 + n * 16 + lr] = v0[r];
        const int rowl1 = 16 + lg * 4 + r;
        if (rowl1 < LL)
            out1[((size_t)bs * 20 + rowl1) * 256 + n * 16 + lr] = v1[r];
    }
}

// ---------------------------------------------------------------------------
// Pool (proven)
// ---------------------------------------------------------------------------
__global__ __launch_bounds__(256) void nrms_pool_mfma(
    const float* __restrict__ out1,
    const short* __restrict__ kwb,
    const float* __restrict__ keyB,
    const float* __restrict__ query,
    float*       __restrict__ out2)
{
    const int bs   = blockIdx.x;
    const int tid  = threadIdx.x;
    const int wave = tid >> 6;
    const int lane = tid & 63;
    const int lr   = lane & 15;
    const int lg   = lane >> 4;

    __shared__ float mh[LL][257];
    __shared__ short mhb[32][264];
    __shared__ float s2p[32];

    for (int i = tid; i < 12 * 128; i += 256) {
        const int r = 20 + i / 128, c = (i % 128) * 2;
        *reinterpret_cast<int*>(&mhb[r][c]) = 0;
    }
    if (tid < 32) s2p[tid] = 0.f;

    for (int idx = tid; idx < LL * 64; idx += 256) {
        const int l = idx >> 6, h4 = (idx & 63) * 4;
        const float4 v = *reinterpret_cast<const float4*>(out1 + ((size_t)bs * LL + l) * HID + h4);
        mh[l][h4] = v.x; mh[l][h4 + 1] = v.y; mh[l][h4 + 2] = v.z; mh[l][h4 + 3] = v.w;
        mhb[l][h4] = f2b(v.x); mhb[l][h4 + 1] = f2b(v.y);
        mhb[l][h4 + 2] = f2b(v.z); mhb[l][h4 + 3] = f2b(v.w);
    }
    __syncthreads();

    for (int t = wave; t < 26; t += 4) {
        const int mt = t & 1, nt = t >> 1;
        f32x4 acc = {0.f, 0.f, 0.f, 0.f};
        const short* ap = &mhb[mt * 16 + lr][lg * 8];
        const short* bp = kwb + (nt * 16 + lr) * 256 + lg * 8;
        #pragma unroll
        for (int k = 0; k < 8; ++k) {
            bf16x8 a = *reinterpret_cast<const bf16x8*>(ap + k * 32);
            bf16x8 b = *reinterpret_cast<const bf16x8*>(bp + k * 32);
            acc = __builtin_amdgcn_mfma_f32_16x16x32_bf16(a, b, acc, 0, 0, 0);
        }
        const int d = nt * 16 + lr;
        const float qd = (d < QD) ? query[d] : 0.f;
        const float kb = (d < QD) ? keyB[d] : 0.f;
        float vals[4];
        #pragma unroll
        for (int r = 0; r < 4; ++r) vals[r] = qd * ftanh(acc[r] + kb);
        #pragma unroll
        for (int off = 1; off < 16; off <<= 1) {
            #pragma unroll
            for (int r = 0; r < 4; ++r) vals[r] += __shfl_xor(vals[r], off);
        }
        if (lr == 0) {
            #pragma unroll
            for (int r = 0; r < 4; ++r)
                atomicAdd(&s2p[mt * 16 + lg * 4 + r], vals[r]);
        }
    }
    __syncthreads();

    if (tid == 0) {
        float mx = -1e30f;
        #pragma unroll
        for (int l = 0; l < LL; ++l) mx = fmaxf(mx, s2p[l] * 0.07071067811865475f);
        float sum = 0.f;
        float e[LL];
        #pragma unroll
        for (int l = 0; l < LL; ++l) { e[l] = __expf(s2p[l] * 0.07071067811865475f - mx); sum += e[l]; }
        const float inv = 1.f / sum;
        #pragma unroll
        for (int l = 0; l < LL; ++l) s2p[l] = e[l] * inv;
    }
    __syncthreads();

    {
        const int h = tid;
        float acc = 0.f;
        #pragma unroll
        for (int l = 0; l < LL; ++l) acc = fmaf(s2p[l], mh[l][h], acc);
        out2[(size_t)bs * HID + h] = acc;
    }
}

// ===========================================================================
// FALLBACK (round-3, 3.4 MB ws)
// ===========================================================================

#define XP 330
#define TP 42
#define AP 34

__global__ __launch_bounds__(1024) void transpose_qw(
    const float* __restrict__ qW, short* __restrict__ wqt)
{
    __shared__ float t[32][33];
    const int n = blockIdx.z;
    const int e0 = blockIdx.x * 32, f0 = blockIdx.y * 32;
    const int tx = threadIdx.x, ty = threadIdx.y;
    const int e = e0 + ty, f = f0 + tx;
    t[ty][tx] = (e < EE && f < EE) ? qW[(size_t)n * EE * EE + e * EE + f] : 0.f;
    __syncthreads();
    const int fo = f0 + ty, eo = e0 + tx;
    if (fo < 304)
        wqt[(size_t)n * 304 * 320 + fo * 320 + eo] = f2b(t[tx][ty]);
}

__global__ void conv_vw(const float* __restrict__ vW, short* __restrict__ wvt) {
    int idx = blockIdx.x * 256 + threadIdx.x;
    if (idx >= NH * VD * 320) return;
    int e = idx % 320;
    int v = (idx / 320) % VD;
    int n = idx / (320 * VD);
    wvt[idx] = (e < EE) ? f2b(vW[(size_t)n * EE * VD + e * VD + v]) : (short)0;
}

__global__ __launch_bounds__(512) void nrms_attn_mfma(
    const int*   __restrict__ news,
    const float* __restrict__ emb,
    const short* __restrict__ wqt,
    const float* __restrict__ qB,
    const short* __restrict__ wvt,
    const float* __restrict__ vB,
    float*       __restrict__ out1)
{
    const int bs   = blockIdx.x;
    const int tid  = threadIdx.x;
    const int wave = tid >> 6;
    const int lane = tid & 63;
    const int lr   = lane & 15;
    const int lg   = lane >> 4;

    __shared__ short xs[32][XP];
    __shared__ short xT[320][TP];
    __shared__ short qs[32][XP];
    __shared__ float sc[32][33];
    __shared__ short at[32][AP];

    {
        int* z = (int*)&xs[0][0];
        for (int i = tid; i < 32 * XP / 2; i += 512) z[i] = 0;
        z = (int*)&qs[0][0];
        for (int i = tid; i < 32 * XP / 2; i += 512) z[i] = 0;
        z = (int*)&xT[0][0];
        for (int i = tid; i < 320 * TP / 2; i += 512) z[i] = 0;
    }
    __syncthreads();

    for (int idx = tid; idx < LL * 75; idx += 512) {
        const int l = idx / 75, e4 = (idx % 75) * 4;
        const int row = news[bs * LL + l];
        const float4 v = *reinterpret_cast<const float4*>(emb + (size_t)row * EE + e4);
        const short b0 = f2b(v.x), b1 = f2b(v.y), b2 = f2b(v.z), b3 = f2b(v.w);
        xs[l][e4] = b0; xs[l][e4 + 1] = b1; xs[l][e4 + 2] = b2; xs[l][e4 + 3] = b3;
        xT[e4][l] = b0; xT[e4 + 1][l] = b1; xT[e4 + 2][l] = b2; xT[e4 + 3][l] = b3;
    }
    __syncthreads();

    for (int n = 0; n < NH; ++n) {
        const short* wq = wqt + (size_t)n * 304 * 320;

        for (int p = wave; p < 19; p += 8) {
            f32x4 acc0 = {0.f, 0.f, 0.f, 0.f};
            f32x4 acc1 = {0.f, 0.f, 0.f, 0.f};
            const short* a0p = &xs[lr][lg * 8];
            const short* a1p = &xs[16 + lr][lg * 8];
            const short* bp  = wq + (p * 16 + lr) * 320 + lg * 8;
            #pragma unroll
            for (int k = 0; k < 10; ++k) {
                bf16x8 b  = *reinterpret_cast<const bf16x8*>(bp + k * 32);
                bf16x8 a0 = *reinterpret_cast<const bf16x8*>(a0p + k * 32);
                bf16x8 a1 = *reinterpret_cast<const bf16x8*>(a1p + k * 32);
                acc0 = __builtin_amdgcn_mfma_f32_16x16x32_bf16(a0, b, acc0, 0, 0, 0);
                acc1 = __builtin_amdgcn_mfma_f32_16x16x32_bf16(a1, b, acc1, 0, 0, 0);
            }
            const int col = p * 16 + lr;
            const float bias = (col < EE) ? qB[n * EE + col] : 0.f;
            #pragma unroll
            for (int r = 0; r < 4; ++r) {
                qs[lg * 4 + r][col]      = f2b(acc0[r] + bias);
                qs[16 + lg * 4 + r][col] = f2b(acc1[r] + bias);
            }
        }
        __syncthreads();

        if (wave < 4) {
            const int mt = wave & 1, nt = wave >> 1;
            f32x4 acc = {0.f, 0.f, 0.f, 0.f};
            const short* ap = &qs[mt * 16 + lr][lg * 8];
            const short* bp = &xs[nt * 16 + lr][lg * 8];
            #pragma unroll
            for (int k = 0; k < 10; ++k) {
                bf16x8 a = *reinterpret_cast<const bf16x8*>(ap + k * 32);
                bf16x8 b = *reinterpret_cast<const bf16x8*>(bp + k * 32);
                acc = __builtin_amdgcn_mfma_f32_16x16x32_bf16(a, b, acc, 0, 0, 0);
            }
            #pragma unroll
            for (int r = 0; r < 4; ++r)
                sc[mt * 16 + lg * 4 + r][nt * 16 + lr] = acc[r] * 0.057735026918962584f;
        }
        __syncthreads();

        if (tid < LL) {
            float mx = -1e30f;
            #pragma unroll
            for (int m = 0; m < LL; ++m) mx = fmaxf(mx, sc[tid][m]);
            float ev[LL], sum = 0.f;
            #pragma unroll
            for (int m = 0; m < LL; ++m) { ev[m] = __expf(sc[tid][m] - mx); sum += ev[m]; }
            const float inv = 1.f / sum;
            #pragma unroll
            for (int m = 0; m < LL; ++m) at[tid][m] = f2b(ev[m] * inv);
            #pragma unroll
            for (int m = LL; m < 32; ++m) at[tid][m] = 0;
        } else if (tid < 32) {
            int* zr = (int*)&at[tid][0];
            #pragma unroll
            for (int m = 0; m < 16; ++m) zr[m] = 0;
        }
        __syncthreads();

        for (int p = wave; p < 19; p += 8) {
            bf16x8 b  = *reinterpret_cast<const bf16x8*>(&xT[p * 16 + lr][lg * 8]);
            bf16x8 a0 = *reinterpret_cast<const bf16x8*>(&at[lr][lg * 8]);
            bf16x8 a1 = *reinterpret_cast<const bf16x8*>(&at[16 + lr][lg * 8]);
            f32x4 z = {0.f, 0.f, 0.f, 0.f};
            f32x4 c0 = __builtin_amdgcn_mfma_f32_16x16x32_bf16(a0, b, z, 0, 0, 0);
            f32x4 c1 = __builtin_amdgcn_mfma_f32_16x16x32_bf16(a1, b, z, 0, 0, 0);
            const int col = p * 16 + lr;
            #pragma unroll
            for (int r = 0; r < 4; ++r) {
                qs[lg * 4 + r][col]      = f2b(c0[r]);
                qs[16 + lg * 4 + r][col] = f2b(c1[r]);
            }
        }
        __syncthreads();

        if (wave < 2) {
            const int mt = wave;
            f32x4 acc = {0.f, 0.f, 0.f, 0.f};
            const short* ap = &qs[mt * 16 + lr][lg * 8];
            const short* bp = wvt + (size_t)n * VD * 320 + lr * 320 + lg * 8;
            #pragma unroll
            for (int k = 0; k < 10; ++k) {
                bf16x8 a = *reinterpret_cast<const bf16x8*>(ap + k * 32);
                bf16x8 b = *reinterpret_cast<const bf16x8*>(bp + k * 32);
                acc = __builtin_amdgcn_mfma_f32_16x16x32_bf16(a, b, acc, 0, 0, 0);
            }
            #pragma unroll
            for (int r = 0; r < 4; ++r) {
                const int row = mt * 16 + lg * 4 + r;
                if (row < LL)
                    out1[((size_t)bs * LL + row) * HID + n * VD + lr] = acc[r] + vB[n * VD + lr];
            }
        }
        __syncthreads();
    }
}

// ===========================================================================

extern "C" void kernel_launch(void* const* d_in, const int* in_sizes, int n_in,
                              void* d_out, int out_size, void* d_ws, size_t ws_size,
                              hipStream_t stream) {
    const int*   news  = (const int*)d_in[0];
    const float* emb   = (const float*)d_in[1];
    const float* qW    = (const float*)d_in[2];
    const float* qB    = (const float*)d_in[3];
    const float* vW    = (const float*)d_in[4];
    const float* vB    = (const float*)d_in[5];
    const float* keyW  = (const float*)d_in[6];
    const float* keyB  = (const float*)d_in[7];
    const float* query = (const float*)d_in[8];

    float* out1 = (float*)d_out;            // news_embedding: 8192000 floats
    float* out2 = out1 + 8192000;           // news_repr: 409600 floats

    // base buffers (shorts): Xb 10.24M, WqT 1.6384M, WvT 81920, xv 8.192M, kwb 53248
    const size_t BASE_SH = 10240000ull + 1638400 + 81920 + 8192000 + 53248;
    const size_t BASE_B  = BASE_SH * 2;                 // 40.4 MB
    const size_t UNIT_B  = 640ull * 5120 * 2;           // 6.55 MB per 640-row q unit

    size_t ucap = (ws_size > BASE_B) ? (ws_size - BASE_B) / UNIT_B : 0;
    int u = (int)((ucap > 50) ? 50 : ucap);             // rows-per-slab = u*640

    if (u >= 1) {
        short* Xb  = (short*)d_ws;
        short* WqT = Xb + 10240000;
        short* WvT = WqT + 1638400;
        short* xv  = WvT + 81920;
        short* kwb = xv + 8192000;
        short* qb  = kwb + 53248;                       // slab q buffer

        hipLaunchKernelGGL(build_xb_lin, dim3(10000), dim3(256), 0, stream, news, emb, Xb);
        hipLaunchKernelGGL(build_wqt_lin, dim3(10, 10, 16), dim3(32, 32), 0, stream, qW, qB, WqT);
        hipLaunchKernelGGL(build_wvt, dim3(320), dim3(256), 0, stream, vW, vB, WvT);
        hipLaunchKernelGGL(conv_kw, dim3(208), dim3(256), 0, stream, keyW, kwb);
        hipLaunchKernelGGL(gemm_xv, dim3(2, 250), dim3(256), 0, stream, Xb, WvT, xv);

        for (int r0 = 0; r0 < 50; r0 += u) {            // 50 units of 640 rows
            const int uu = (u < 50 - r0) ? u : (50 - r0);
            hipLaunchKernelGGL(gemm_q, dim3(40, uu * 5), dim3(256), 0, stream,
                               Xb, WqT, qb, r0 * 640);
            hipLaunchKernelGGL(sv, dim3(uu * 128), dim3(256), 0, stream,
                               Xb, qb, xv, out1, r0 * 32);
        }
        hipLaunchKernelGGL(nrms_pool_mfma, dim3(NBS), dim3(256), 0, stream,
                           out1, kwb, keyB, query, out2);
    } else {
        short* wqt = (short*)d_ws;
        short* wvt = wqt + (size_t)NH * 304 * 320;
        short* kwb = wvt + (size_t)NH * VD * 320;

        hipLaunchKernelGGL(transpose_qw, dim3(10, 10, 16), dim3(32, 32), 0, stream, qW, wqt);
        hipLaunchKernelGGL(conv_vw, dim3(320), dim3(256), 0, stream, vW, wvt);
        hipLaunchKernelGGL(conv_kw, dim3(208), dim3(256), 0, stream, keyW, kwb);
        hipLaunchKernelGGL(nrms_attn_mfma, dim3(NBS), dim3(512), 0, stream,
                           news, emb, wqt, qB, wvt, vB, out1);
        hipLaunchKernelGGL(nrms_pool_mfma, dim3(NBS), dim3(256), 0, stream,
                           out1, kwb, keyB, query, out2);
    }
}